// Round 3
// baseline (7074.680 us; speedup 1.0000x reference)
//
#include <hip/hip_runtime.h>
#include <hip/hip_bf16.h>

#define STR 194   // padded LDS row stride (bf16 elems): odd dword stride -> conflict-free

typedef __hip_bfloat16 bf16;

__device__ __forceinline__ float b2f(bf16 v) { return __bfloat162float(v); }
__device__ __forceinline__ bf16 f2b(float v) { return __float2bfloat16(v); }

// ---------------------------------------------------------------------------
// Kernel 1: per-window fused  LN1 -> kv GEMM -> attention -> proj -> residual
// grid = 4096 windows (B=2 * 2048), block = 256.  Writes x (f32) to xout.
// ---------------------------------------------------------------------------
__global__ __launch_bounds__(256) void k_attn(
    const float* __restrict__ skip, const float* __restrict__ xup,
    const float* __restrict__ g1,   const float* __restrict__ be1,
    const float* __restrict__ Wkv,  const float* __restrict__ bkv,
    const float* __restrict__ Wproj,const float* __restrict__ bproj,
    const float* __restrict__ btab, const int*  __restrict__ relidx,
    float* __restrict__ xout)
{
    __shared__ __align__(16) bf16 sQ[64 * STR];
    __shared__ __align__(16) bf16 sK[64 * STR];
    __shared__ __align__(16) bf16 sV[64 * STR];
    __shared__ __align__(16) bf16 sO[64 * STR];
    __shared__ __align__(16) float sPool[64 * STR / 2];   // s_ln (bf16) then scores (f32)
    __shared__ __align__(16) bf16 sWst[12288];            // weight staging (24576 B)
    __shared__ int sRow[64];

    const int tid = threadIdx.x;
    const int w = blockIdx.x;
    const int b = w >> 11;
    const int widx = w & 2047;
    const int d0 = widx >> 8, h0 = (widx >> 4) & 15, w0 = widx & 15;

    if (tid < 64) {
        int t = tid;
        int wd = t >> 4, wh = (t >> 2) & 3, ww = t & 3;
        int l = (d0 * 4 + wd) * 4096 + (h0 * 4 + wh) * 64 + (w0 * 4 + ww);
        sRow[t] = b * 131072 + l;
    }
    __syncthreads();

    bf16* sS = (bf16*)sPool;

    // ---- Phase A: load raw windows (f32, vectorized), round to bf16 in LDS ----
    for (int i = 0; i < 12; ++i) {
        int ci = tid + i * 256;            // 3072 chunks of 4 f32
        int t = ci / 48, c = (ci % 48) * 4;
        int gbase = sRow[t] * 192 + c;
        float4 uu = *(const float4*)(xup + gbase);
        float4 us = *(const float4*)(skip + gbase);
        sQ[t * STR + c + 0] = f2b(uu.x); sQ[t * STR + c + 1] = f2b(uu.y);
        sQ[t * STR + c + 2] = f2b(uu.z); sQ[t * STR + c + 3] = f2b(uu.w);
        sS[t * STR + c + 0] = f2b(us.x); sS[t * STR + c + 1] = f2b(us.y);
        sS[t * STR + c + 2] = f2b(us.z); sS[t * STR + c + 3] = f2b(us.w);
    }
    __syncthreads();

    // ---- LN1 on both tensors, in place; fold 32^-0.5 into Q ----
    {
        int t = tid >> 2, sub = tid & 3;
        float su = 0, squ = 0, ss = 0, sqs = 0;
        for (int j = 0; j < 48; ++j) {
            int c = sub + 4 * j;
            float u = b2f(sQ[t * STR + c]);
            float s = b2f(sS[t * STR + c]);
            su += u; squ += u * u; ss += s; sqs += s * s;
        }
        su += __shfl_xor(su, 1);  su += __shfl_xor(su, 2);
        squ += __shfl_xor(squ, 1); squ += __shfl_xor(squ, 2);
        ss += __shfl_xor(ss, 1);  ss += __shfl_xor(ss, 2);
        sqs += __shfl_xor(sqs, 1); sqs += __shfl_xor(sqs, 2);
        const float inv192 = 1.f / 192.f;
        float muU = su * inv192, vU = squ * inv192 - muU * muU;
        float muS = ss * inv192, vS = sqs * inv192 - muS * muS;
        float rU = rsqrtf(vU + 1e-5f), rS = rsqrtf(vS + 1e-5f);
        const float scale = 0.17677669529663687f;   // 32^-0.5
        for (int j = 0; j < 48; ++j) {
            int c = sub + 4 * j;
            float g = g1[c], be = be1[c];
            float u = b2f(sQ[t * STR + c]);
            float s = b2f(sS[t * STR + c]);
            sQ[t * STR + c] = f2b(((u - muU) * rU * g + be) * scale);
            sS[t * STR + c] = f2b((s - muS) * rS * g + be);
        }
    }
    __syncthreads();

    // ---- Phase B: kv = s_ln @ Wkv + bkv  (Wkv staged bf16, 32-row slices) ----
    {
        int t = tid >> 2, sub = tid & 3;
        float acc[96];
        #pragma unroll
        for (int i = 0; i < 96; ++i) acc[i] = 0.f;
        for (int sl = 0; sl < 6; ++sl) {
            int kk0 = sl * 32;
            for (int i = 0; i < 12; ++i) {            // 32*384 = 12288 elems, 4/chunk
                int ch = tid + i * 256;
                float4 w4 = *(const float4*)(Wkv + kk0 * 384 + ch * 4);
                bf16 tmp[4] = {f2b(w4.x), f2b(w4.y), f2b(w4.z), f2b(w4.w)};
                *(uint2*)(sWst + ch * 4) = *(uint2*)tmp;
            }
            __syncthreads();
            for (int kk = 0; kk < 32; ++kk) {
                float s = b2f(sS[t * STR + kk0 + kk]);
                #pragma unroll
                for (int ch = 0; ch < 12; ++ch) {
                    int cb = sub * 96 + ch * 8;
                    uint4 wv = *(const uint4*)(sWst + kk * 384 + cb);
                    const bf16* wp = (const bf16*)&wv;
                    #pragma unroll
                    for (int j = 0; j < 8; ++j) acc[ch * 8 + j] += s * b2f(wp[j]);
                }
            }
            __syncthreads();
        }
        #pragma unroll
        for (int ch = 0; ch < 12; ++ch)
            #pragma unroll
            for (int j = 0; j < 8; ++j) {
                int c = sub * 96 + ch * 8 + j;
                float v = acc[ch * 8 + j] + bkv[c];
                if (c < 192) sK[t * STR + c]       = f2b(v);
                else         sV[t * STR + c - 192] = f2b(v);
            }
    }
    __syncthreads();

    // ---- Phase C: per-head scores -> softmax -> PV ----
    float* scoresF = sPool;    // s_ln dead now
    for (int h = 0; h < 6; ++h) {
        for (int o = tid; o < 4096; o += 256) {
            int qt = o >> 6, kt = o & 63;
            float a = btab[relidx[o] * 6 + h];
            int qb = qt * STR + h * 32, kb = kt * STR + h * 32;
            for (int d = 0; d < 32; ++d)
                a += b2f(sQ[qb + d]) * b2f(sK[kb + d]);
            scoresF[o] = a;
        }
        __syncthreads();
        {
            int t = tid >> 2, sub = tid & 3;
            float vals[16];
            float m = -1e30f;
            #pragma unroll
            for (int j = 0; j < 16; ++j) { vals[j] = scoresF[t * 64 + sub + 4 * j]; m = fmaxf(m, vals[j]); }
            m = fmaxf(m, __shfl_xor(m, 1)); m = fmaxf(m, __shfl_xor(m, 2));
            float sum = 0;
            #pragma unroll
            for (int j = 0; j < 16; ++j) { vals[j] = __expf(vals[j] - m); sum += vals[j]; }
            sum += __shfl_xor(sum, 1); sum += __shfl_xor(sum, 2);
            float inv = 1.f / sum;
            #pragma unroll
            for (int j = 0; j < 16; ++j) scoresF[t * 64 + sub + 4 * j] = vals[j] * inv;
        }
        __syncthreads();
        for (int o2 = tid; o2 < 2048; o2 += 256) {
            int qt = o2 >> 5, d = o2 & 31;
            float a = 0;
            int vb = h * 32 + d;
            for (int kt = 0; kt < 64; ++kt)
                a += scoresF[qt * 64 + kt] * b2f(sV[kt * STR + vb]);
            sO[qt * STR + h * 32 + d] = f2b(a);
        }
        __syncthreads();
    }

    // ---- Phase D: proj + bias + skip-residual -> x (f32, to xout=d_out) ----
    {
        int t = tid >> 2, sub = tid & 3;
        float acc[48];
        #pragma unroll
        for (int i = 0; i < 48; ++i) acc[i] = 0.f;
        for (int sl = 0; sl < 3; ++sl) {
            int kk0 = sl * 64;
            for (int i = 0; i < 12; ++i) {            // 64*192 = 12288 elems
                int ch = tid + i * 256;
                float4 w4 = *(const float4*)(Wproj + kk0 * 192 + ch * 4);
                bf16 tmp[4] = {f2b(w4.x), f2b(w4.y), f2b(w4.z), f2b(w4.w)};
                *(uint2*)(sWst + ch * 4) = *(uint2*)tmp;
            }
            __syncthreads();
            for (int kk = 0; kk < 64; ++kk) {
                float ov = b2f(sO[t * STR + kk0 + kk]);
                #pragma unroll
                for (int ch = 0; ch < 6; ++ch) {
                    int cb = sub * 48 + ch * 8;
                    uint4 wv = *(const uint4*)(sWst + kk * 192 + cb);
                    const bf16* wp = (const bf16*)&wv;
                    #pragma unroll
                    for (int j = 0; j < 8; ++j) acc[ch * 8 + j] += ov * b2f(wp[j]);
                }
            }
            __syncthreads();
        }
        int rbase = sRow[t] * 192;
        #pragma unroll
        for (int ch = 0; ch < 12; ++ch) {
            int cb = sub * 48 + ch * 4;
            float4 sv = *(const float4*)(skip + rbase + cb);
            float4 ov;
            ov.x = acc[ch * 4 + 0] + bproj[cb + 0] + sv.x;
            ov.y = acc[ch * 4 + 1] + bproj[cb + 1] + sv.y;
            ov.z = acc[ch * 4 + 2] + bproj[cb + 2] + sv.z;
            ov.w = acc[ch * 4 + 3] + bproj[cb + 3] + sv.w;
            *(float4*)(xout + rbase + cb) = ov;
        }
    }
}

// ---------------------------------------------------------------------------
// Kernel 2 (in-place on d_out): out = x + (gelu(LN2(x) @ W1 + b1) @ W2 + b2)
// grid = 8192 (32 rows/block), block = 256
// ---------------------------------------------------------------------------
__global__ __launch_bounds__(256) void k_mlp(
    float* __restrict__ xio,
    const float* __restrict__ g2, const float* __restrict__ be2,
    const float* __restrict__ W1, const float* __restrict__ b1,
    const float* __restrict__ W2, const float* __restrict__ b2)
{
    __shared__ __align__(16) bf16 sX[32 * STR];   // xln; later W2 staging (6144 <= 6208)
    __shared__ __align__(16) bf16 sH[32 * 776];   // hidden; first W1 staging (24576 <= 24832)
    const int tid = threadIdx.x;
    const int rowbase = blockIdx.x * 32;

    // load 32 rows of x (f32 -> bf16 in LDS)
    for (int i = 0; i < 6; ++i) {
        int ch = tid + i * 256;                    // 1536 chunks of 4
        int t = ch / 48, c = (ch % 48) * 4;
        float4 uu = *(const float4*)(xio + (rowbase + t) * 192 + c);
        sX[t * STR + c + 0] = f2b(uu.x); sX[t * STR + c + 1] = f2b(uu.y);
        sX[t * STR + c + 2] = f2b(uu.z); sX[t * STR + c + 3] = f2b(uu.w);
    }
    __syncthreads();
    // LN2 in place
    {
        int r = tid >> 3, sub = tid & 7;
        float s = 0, sq = 0;
        for (int j = 0; j < 24; ++j) {
            int c = sub + 8 * j;
            float v = b2f(sX[r * STR + c]);
            s += v; sq += v * v;
        }
        s += __shfl_xor(s, 1); s += __shfl_xor(s, 2); s += __shfl_xor(s, 4);
        sq += __shfl_xor(sq, 1); sq += __shfl_xor(sq, 2); sq += __shfl_xor(sq, 4);
        float mu = s * (1.f / 192.f), var = sq * (1.f / 192.f) - mu * mu;
        float rs = rsqrtf(var + 1e-5f);
        for (int j = 0; j < 24; ++j) {
            int c = sub + 8 * j;
            float v = b2f(sX[r * STR + c]);
            sX[r * STR + c] = f2b((v - mu) * rs * g2[c] + be2[c]);
        }
    }
    __syncthreads();
    // H = gelu(xln @ W1 + b1)
    {
        int r = tid >> 3, sub = tid & 7;
        float acc[96];
        #pragma unroll
        for (int i = 0; i < 96; ++i) acc[i] = 0.f;
        bf16* stg = sH;
        for (int sl = 0; sl < 6; ++sl) {
            int kk0 = sl * 32;
            for (int i = 0; i < 24; ++i) {            // 32*768 = 24576 elems, 4/chunk
                int ch = tid + i * 256;
                float4 w4 = *(const float4*)(W1 + kk0 * 768 + ch * 4);
                bf16 tmp[4] = {f2b(w4.x), f2b(w4.y), f2b(w4.z), f2b(w4.w)};
                *(uint2*)(stg + ch * 4) = *(uint2*)tmp;
            }
            __syncthreads();
            for (int kk = 0; kk < 32; ++kk) {
                float xv = b2f(sX[r * STR + kk0 + kk]);
                #pragma unroll
                for (int ch = 0; ch < 12; ++ch) {
                    int cb = sub * 96 + ch * 8;
                    uint4 wv = *(const uint4*)(stg + kk * 768 + cb);
                    const bf16* wp = (const bf16*)&wv;
                    #pragma unroll
                    for (int j = 0; j < 8; ++j) acc[ch * 8 + j] += xv * b2f(wp[j]);
                }
            }
            __syncthreads();
        }
        #pragma unroll
        for (int ch = 0; ch < 12; ++ch)
            #pragma unroll
            for (int j = 0; j < 8; ++j) {
                int c = sub * 96 + ch * 8 + j;
                float v = acc[ch * 8 + j] + b1[c];
                float ge = 0.5f * v * (1.f + erff(v * 0.70710678118654752f));
                sH[r * 776 + c] = f2b(ge);
            }
    }
    __syncthreads();
    // out = x + H @ W2 + b2   (x re-read f32 from global; in-place store)
    {
        int r = tid >> 3, sub = tid & 7;
        float acc[24];
        #pragma unroll
        for (int i = 0; i < 24; ++i) acc[i] = 0.f;
        bf16* stg = sX;   // xln dead
        for (int sl = 0; sl < 24; ++sl) {
            int kk0 = sl * 32;
            for (int i = 0; i < 6; ++i) {             // 32*192 = 6144 elems, 4/chunk
                int ch = tid + i * 256;
                float4 w4 = *(const float4*)(W2 + kk0 * 192 + ch * 4);
                bf16 tmp[4] = {f2b(w4.x), f2b(w4.y), f2b(w4.z), f2b(w4.w)};
                *(uint2*)(stg + ch * 4) = *(uint2*)tmp;
            }
            __syncthreads();
            for (int kk = 0; kk < 32; ++kk) {
                float hv = b2f(sH[r * 776 + kk0 + kk]);
                #pragma unroll
                for (int ch = 0; ch < 3; ++ch) {
                    int cb = sub * 24 + ch * 8;
                    uint4 wv = *(const uint4*)(stg + kk * 192 + cb);
                    const bf16* wp = (const bf16*)&wv;
                    #pragma unroll
                    for (int j = 0; j < 8; ++j) acc[ch * 8 + j] += hv * b2f(wp[j]);
                }
            }
            __syncthreads();
        }
        int gbase = (rowbase + r) * 192;
        #pragma unroll
        for (int ch = 0; ch < 6; ++ch) {
            int cb = sub * 24 + ch * 4;
            float4 xv = *(const float4*)(xio + gbase + cb);
            float4 ov;
            ov.x = acc[ch * 4 + 0] + b2[cb + 0] + xv.x;
            ov.y = acc[ch * 4 + 1] + b2[cb + 1] + xv.y;
            ov.z = acc[ch * 4 + 2] + b2[cb + 2] + xv.z;
            ov.w = acc[ch * 4 + 3] + b2[cb + 3] + xv.w;
            *(float4*)(xio + gbase + cb) = ov;
        }
    }
}

extern "C" void kernel_launch(void* const* d_in, const int* in_sizes, int n_in,
                              void* d_out, int out_size, void* d_ws, size_t ws_size,
                              hipStream_t stream) {
    const float* skip   = (const float*)d_in[0];
    const float* xup    = (const float*)d_in[1];
    const float* g1     = (const float*)d_in[2];
    const float* be1    = (const float*)d_in[3];
    const float* g2     = (const float*)d_in[4];
    const float* be2    = (const float*)d_in[5];
    const float* Wkv    = (const float*)d_in[6];
    const float* bkv    = (const float*)d_in[7];
    const float* Wproj  = (const float*)d_in[8];
    const float* bproj  = (const float*)d_in[9];
    const float* btab   = (const float*)d_in[10];
    const int*  relidx  = (const int*)d_in[11];
    const float* W1     = (const float*)d_in[12];
    const float* b1     = (const float*)d_in[13];
    const float* W2     = (const float*)d_in[14];
    const float* b2     = (const float*)d_in[15];
    float* xio = (float*)d_out;   // x lives in d_out; k_mlp updates it in place

    k_attn<<<4096, 256, 0, stream>>>(skip, xup, g1, be1, Wkv, bkv, Wproj, bproj, btab, relidx, xio);
    k_mlp<<<8192, 256, 0, stream>>>(xio, g2, be2, W1, b1, W2, b2);
}

// Round 5
// 4243.382 us; speedup vs baseline: 1.6672x; 1.6672x over previous
//
#include <hip/hip_runtime.h>
#include <hip/hip_bf16.h>

#define STR 194   // padded LDS row stride for k_attn (bf16 elems)

typedef __hip_bfloat16 bf16;
typedef short s8v __attribute__((ext_vector_type(8)));   // 8 bf16 (4 VGPRs)
typedef float f32x4 __attribute__((ext_vector_type(4)));

__device__ __forceinline__ float b2f(bf16 v) { return __bfloat162float(v); }
__device__ __forceinline__ bf16 f2b(float v) { return __float2bfloat16(v); }

__device__ __forceinline__ float gelu_f(float v) {
    // exact-gelu via Abramowitz-Stegun 7.1.26 erf (|eps| <= 1.5e-7)
    float z = fabsf(v) * 0.70710678118654752f;
    float t = 1.f / (1.f + 0.3275911f * z);
    float poly = t * (0.254829592f + t * (-0.284496736f + t * (1.421413741f +
                 t * (-1.453152027f + t * 1.061405429f))));
    float erfz = 1.f - poly * __expf(-z * z);
    erfz = copysignf(erfz, v);
    return 0.5f * v * (1.f + erfz);
}

// ---------------------------------------------------------------------------
// Kernel 1 (unchanged, passing since R3): LN1 -> kv -> attn -> proj -> +skip
// grid = 4096 windows, block = 256.  Writes x (f32) to xout (= d_out).
// ---------------------------------------------------------------------------
__global__ __launch_bounds__(256) void k_attn(
    const float* __restrict__ skip, const float* __restrict__ xup,
    const float* __restrict__ g1,   const float* __restrict__ be1,
    const float* __restrict__ Wkv,  const float* __restrict__ bkv,
    const float* __restrict__ Wproj,const float* __restrict__ bproj,
    const float* __restrict__ btab, const int*  __restrict__ relidx,
    float* __restrict__ xout)
{
    __shared__ __align__(16) bf16 sQ[64 * STR];
    __shared__ __align__(16) bf16 sK[64 * STR];
    __shared__ __align__(16) bf16 sV[64 * STR];
    __shared__ __align__(16) bf16 sO[64 * STR];
    __shared__ __align__(16) float sPool[64 * STR / 2];
    __shared__ __align__(16) bf16 sWst[12288];
    __shared__ int sRow[64];

    const int tid = threadIdx.x;
    const int w = blockIdx.x;
    const int b = w >> 11;
    const int widx = w & 2047;
    const int d0 = widx >> 8, h0 = (widx >> 4) & 15, w0 = widx & 15;

    if (tid < 64) {
        int t = tid;
        int wd = t >> 4, wh = (t >> 2) & 3, ww = t & 3;
        int l = (d0 * 4 + wd) * 4096 + (h0 * 4 + wh) * 64 + (w0 * 4 + ww);
        sRow[t] = b * 131072 + l;
    }
    __syncthreads();

    bf16* sS = (bf16*)sPool;

    for (int i = 0; i < 12; ++i) {
        int ci = tid + i * 256;
        int t = ci / 48, c = (ci % 48) * 4;
        int gbase = sRow[t] * 192 + c;
        float4 uu = *(const float4*)(xup + gbase);
        float4 us = *(const float4*)(skip + gbase);
        sQ[t * STR + c + 0] = f2b(uu.x); sQ[t * STR + c + 1] = f2b(uu.y);
        sQ[t * STR + c + 2] = f2b(uu.z); sQ[t * STR + c + 3] = f2b(uu.w);
        sS[t * STR + c + 0] = f2b(us.x); sS[t * STR + c + 1] = f2b(us.y);
        sS[t * STR + c + 2] = f2b(us.z); sS[t * STR + c + 3] = f2b(us.w);
    }
    __syncthreads();

    {
        int t = tid >> 2, sub = tid & 3;
        float su = 0, squ = 0, ss = 0, sqs = 0;
        for (int j = 0; j < 48; ++j) {
            int c = sub + 4 * j;
            float u = b2f(sQ[t * STR + c]);
            float s = b2f(sS[t * STR + c]);
            su += u; squ += u * u; ss += s; sqs += s * s;
        }
        su += __shfl_xor(su, 1);  su += __shfl_xor(su, 2);
        squ += __shfl_xor(squ, 1); squ += __shfl_xor(squ, 2);
        ss += __shfl_xor(ss, 1);  ss += __shfl_xor(ss, 2);
        sqs += __shfl_xor(sqs, 1); sqs += __shfl_xor(sqs, 2);
        const float inv192 = 1.f / 192.f;
        float muU = su * inv192, vU = squ * inv192 - muU * muU;
        float muS = ss * inv192, vS = sqs * inv192 - muS * muS;
        float rU = rsqrtf(vU + 1e-5f), rS = rsqrtf(vS + 1e-5f);
        const float scale = 0.17677669529663687f;
        for (int j = 0; j < 48; ++j) {
            int c = sub + 4 * j;
            float g = g1[c], be = be1[c];
            float u = b2f(sQ[t * STR + c]);
            float s = b2f(sS[t * STR + c]);
            sQ[t * STR + c] = f2b(((u - muU) * rU * g + be) * scale);
            sS[t * STR + c] = f2b((s - muS) * rS * g + be);
        }
    }
    __syncthreads();

    {
        int t = tid >> 2, sub = tid & 3;
        float acc[96];
        #pragma unroll
        for (int i = 0; i < 96; ++i) acc[i] = 0.f;
        for (int sl = 0; sl < 6; ++sl) {
            int kk0 = sl * 32;
            for (int i = 0; i < 12; ++i) {
                int ch = tid + i * 256;
                float4 w4 = *(const float4*)(Wkv + kk0 * 384 + ch * 4);
                bf16 tmp[4] = {f2b(w4.x), f2b(w4.y), f2b(w4.z), f2b(w4.w)};
                *(uint2*)(sWst + ch * 4) = *(uint2*)tmp;
            }
            __syncthreads();
            for (int kk = 0; kk < 32; ++kk) {
                float s = b2f(sS[t * STR + kk0 + kk]);
                #pragma unroll
                for (int ch = 0; ch < 12; ++ch) {
                    int cb = sub * 96 + ch * 8;
                    uint4 wv = *(const uint4*)(sWst + kk * 384 + cb);
                    const bf16* wp = (const bf16*)&wv;
                    #pragma unroll
                    for (int j = 0; j < 8; ++j) acc[ch * 8 + j] += s * b2f(wp[j]);
                }
            }
            __syncthreads();
        }
        #pragma unroll
        for (int ch = 0; ch < 12; ++ch)
            #pragma unroll
            for (int j = 0; j < 8; ++j) {
                int c = sub * 96 + ch * 8 + j;
                float v = acc[ch * 8 + j] + bkv[c];
                if (c < 192) sK[t * STR + c]       = f2b(v);
                else         sV[t * STR + c - 192] = f2b(v);
            }
    }
    __syncthreads();

    float* scoresF = sPool;
    for (int h = 0; h < 6; ++h) {
        for (int o = tid; o < 4096; o += 256) {
            int qt = o >> 6, kt = o & 63;
            float a = btab[relidx[o] * 6 + h];
            int qb = qt * STR + h * 32, kb = kt * STR + h * 32;
            for (int d = 0; d < 32; ++d)
                a += b2f(sQ[qb + d]) * b2f(sK[kb + d]);
            scoresF[o] = a;
        }
        __syncthreads();
        {
            int t = tid >> 2, sub = tid & 3;
            float vals[16];
            float m = -1e30f;
            #pragma unroll
            for (int j = 0; j < 16; ++j) { vals[j] = scoresF[t * 64 + sub + 4 * j]; m = fmaxf(m, vals[j]); }
            m = fmaxf(m, __shfl_xor(m, 1)); m = fmaxf(m, __shfl_xor(m, 2));
            float sum = 0;
            #pragma unroll
            for (int j = 0; j < 16; ++j) { vals[j] = __expf(vals[j] - m); sum += vals[j]; }
            sum += __shfl_xor(sum, 1); sum += __shfl_xor(sum, 2);
            float inv = 1.f / sum;
            #pragma unroll
            for (int j = 0; j < 16; ++j) scoresF[t * 64 + sub + 4 * j] = vals[j] * inv;
        }
        __syncthreads();
        for (int o2 = tid; o2 < 2048; o2 += 256) {
            int qt = o2 >> 5, d = o2 & 31;
            float a = 0;
            int vb = h * 32 + d;
            for (int kt = 0; kt < 64; ++kt)
                a += scoresF[qt * 64 + kt] * b2f(sV[kt * STR + vb]);
            sO[qt * STR + h * 32 + d] = f2b(a);
        }
        __syncthreads();
    }

    {
        int t = tid >> 2, sub = tid & 3;
        float acc[48];
        #pragma unroll
        for (int i = 0; i < 48; ++i) acc[i] = 0.f;
        for (int sl = 0; sl < 3; ++sl) {
            int kk0 = sl * 64;
            for (int i = 0; i < 12; ++i) {
                int ch = tid + i * 256;
                float4 w4 = *(const float4*)(Wproj + kk0 * 192 + ch * 4);
                bf16 tmp[4] = {f2b(w4.x), f2b(w4.y), f2b(w4.z), f2b(w4.w)};
                *(uint2*)(sWst + ch * 4) = *(uint2*)tmp;
            }
            __syncthreads();
            for (int kk = 0; kk < 64; ++kk) {
                float ov = b2f(sO[t * STR + kk0 + kk]);
                #pragma unroll
                for (int ch = 0; ch < 6; ++ch) {
                    int cb = sub * 48 + ch * 8;
                    uint4 wv = *(const uint4*)(sWst + kk * 192 + cb);
                    const bf16* wp = (const bf16*)&wv;
                    #pragma unroll
                    for (int j = 0; j < 8; ++j) acc[ch * 8 + j] += ov * b2f(wp[j]);
                }
            }
            __syncthreads();
        }
        int rbase = sRow[t] * 192;
        #pragma unroll
        for (int ch = 0; ch < 12; ++ch) {
            int cb = sub * 48 + ch * 4;
            float4 sv = *(const float4*)(skip + rbase + cb);
            float4 ov;
            ov.x = acc[ch * 4 + 0] + bproj[cb + 0] + sv.x;
            ov.y = acc[ch * 4 + 1] + bproj[cb + 1] + sv.y;
            ov.z = acc[ch * 4 + 2] + bproj[cb + 2] + sv.z;
            ov.w = acc[ch * 4 + 3] + bproj[cb + 3] + sv.w;
            *(float4*)(xout + rbase + cb) = ov;
        }
    }
}

// ---------------------------------------------------------------------------
// Kernel 2 (MFMA, m97-verified fragment pattern): out = x + MLP(LN2(x)), in place.
// grid = 2048 (128 rows/block), block = 256 (4 waves).
// A-frag: row=lane&15, k=(lane>>4)*8+e contiguous from padded row-major LDS.
// B-frag: col=lane&15, same k, from TRANSPOSED padded staging [n][k].
// ---------------------------------------------------------------------------
__global__ __launch_bounds__(256, 2) void k_mlp(
    float* __restrict__ xio,
    const float* __restrict__ g2, const float* __restrict__ be2,
    const float* __restrict__ W1, const float* __restrict__ b1,
    const float* __restrict__ W2, const float* __restrict__ b2)
{
    __shared__ __align__(16) bf16 sX[128 * 200];  // xln rows padded to 200 (400B, 2-way banks)
    __shared__ __align__(16) bf16 sH[128 * 40];   // hidden chunk, rows padded to 40 (80B)
    __shared__ __align__(16) bf16 sWt[9216];      // W1t[32][200] (6400) or W2t[192][48] (9216)

    const int tid = threadIdx.x;
    const int lane = tid & 63;
    const int wv = tid >> 6;
    const int g = lane >> 4;            // k-group
    const int lr = lane & 15;           // A row / B col within 16-tile
    const int rowbase = blockIdx.x * 128;

    // ---- prologue: x (f32) -> bf16 into sX ----
    for (int i = 0; i < 24; ++i) {
        int ci = tid + i * 256;               // 6144 float4s = 128 x 48
        int r = ci / 48, j = ci % 48;
        float4 v = *(const float4*)(xio + (rowbase + r) * 192 + 4 * j);
        bf16 t4[4] = {f2b(v.x), f2b(v.y), f2b(v.z), f2b(v.w)};
        *(uint2*)(sX + r * 200 + 4 * j) = *(uint2*)t4;
    }
    __syncthreads();

    // ---- LN2 in place (2 threads per row) ----
    {
        int r = tid >> 1, sub = tid & 1;
        int cb = sub * 96;
        float s = 0, sq = 0;
        for (int j = 0; j < 24; ++j) {
            int c = cb + 4 * j;
            uint2 u = *(uint2*)(sX + r * 200 + c);
            const bf16* p = (const bf16*)&u;
            #pragma unroll
            for (int e = 0; e < 4; ++e) { float v = b2f(p[e]); s += v; sq += v * v; }
        }
        s += __shfl_xor(s, 1); sq += __shfl_xor(sq, 1);
        float mu = s * (1.f / 192.f), var = sq * (1.f / 192.f) - mu * mu;
        float rs = rsqrtf(var + 1e-5f);
        for (int j = 0; j < 24; ++j) {
            int c = cb + 4 * j;
            uint2 u = *(uint2*)(sX + r * 200 + c);
            const bf16* p = (const bf16*)&u;
            float4 gg = *(const float4*)(g2 + c);
            float4 be = *(const float4*)(be2 + c);
            bf16 t4[4] = { f2b((b2f(p[0]) - mu) * rs * gg.x + be.x),
                           f2b((b2f(p[1]) - mu) * rs * gg.y + be.y),
                           f2b((b2f(p[2]) - mu) * rs * gg.z + be.z),
                           f2b((b2f(p[3]) - mu) * rs * gg.w + be.w) };
            *(uint2*)(sX + r * 200 + c) = *(uint2*)t4;
        }
    }

    f32x4 accC[2][12];
    #pragma unroll
    for (int mi = 0; mi < 2; ++mi)
        #pragma unroll
        for (int nt = 0; nt < 12; ++nt) accC[mi][nt] = (f32x4){0.f, 0.f, 0.f, 0.f};

    for (int ch = 0; ch < 24; ++ch) {
        int n0 = ch * 32;     // hidden-col block (W1 cols, W2 rows)
        __syncthreads();      // sWt (prev GEMM2 reads) -> safe to restage; also LN2 on first iter

        // stage W1t[n][k] = W1[k][n0+n], n<32, k<192, row pad 200
        for (int i = 0; i < 6; ++i) {
            int ci = tid + i * 256;           // 1536 float4s (192 k x 8 j)
            int k = ci >> 3, j = ci & 7;
            float4 v = *(const float4*)(W1 + k * 768 + n0 + 4 * j);
            sWt[(4 * j + 0) * 200 + k] = f2b(v.x);
            sWt[(4 * j + 1) * 200 + k] = f2b(v.y);
            sWt[(4 * j + 2) * 200 + k] = f2b(v.z);
            sWt[(4 * j + 3) * 200 + k] = f2b(v.w);
        }
        __syncthreads();

        // ---- GEMM1: accH = X(128x192) . W1chunk(192x32) ----
        f32x4 accH[2][2];
        #pragma unroll
        for (int mi = 0; mi < 2; ++mi)
            #pragma unroll
            for (int nt = 0; nt < 2; ++nt) accH[mi][nt] = (f32x4){0.f, 0.f, 0.f, 0.f};

        #pragma unroll
        for (int ks = 0; ks < 6; ++ks) {
            s8v a0 = *(const s8v*)(sX + (wv * 16 + lr) * 200 + ks * 32 + g * 8);
            s8v a1 = *(const s8v*)(sX + (wv * 16 + 64 + lr) * 200 + ks * 32 + g * 8);
            s8v b0 = *(const s8v*)(sWt + lr * 200 + ks * 32 + g * 8);
            s8v b1f = *(const s8v*)(sWt + (16 + lr) * 200 + ks * 32 + g * 8);
            accH[0][0] = __builtin_amdgcn_mfma_f32_16x16x32_bf16(a0, b0,  accH[0][0], 0, 0, 0);
            accH[0][1] = __builtin_amdgcn_mfma_f32_16x16x32_bf16(a0, b1f, accH[0][1], 0, 0, 0);
            accH[1][0] = __builtin_amdgcn_mfma_f32_16x16x32_bf16(a1, b0,  accH[1][0], 0, 0, 0);
            accH[1][1] = __builtin_amdgcn_mfma_f32_16x16x32_bf16(a1, b1f, accH[1][1], 0, 0, 0);
        }

        // ---- gelu + store H chunk ----
        #pragma unroll
        for (int mi = 0; mi < 2; ++mi)
            #pragma unroll
            for (int nt = 0; nt < 2; ++nt) {
                float bb = b1[n0 + nt * 16 + lr];
                #pragma unroll
                for (int e = 0; e < 4; ++e) {
                    int row = wv * 16 + mi * 64 + g * 4 + e;   // C/D: row=(lane>>4)*4+reg
                    int hc = nt * 16 + lr;                     //      col=lane&15
                    sH[row * 40 + hc] = f2b(gelu_f(accH[mi][nt][e] + bb));
                }
            }
        __syncthreads();     // sH written; also sWt reads (GEMM1) done -> restage

        // stage W2t[n][kh] = W2[n0+kh][n], n<192, kh<32, row pad 48
        for (int i = 0; i < 6; ++i) {
            int ci = tid + i * 256;           // 1536 float4s (32 kh x 48 j)
            int kh = ci / 48, j = ci % 48;
            float4 v = *(const float4*)(W2 + (n0 + kh) * 192 + 4 * j);
            sWt[(4 * j + 0) * 48 + kh] = f2b(v.x);
            sWt[(4 * j + 1) * 48 + kh] = f2b(v.y);
            sWt[(4 * j + 2) * 48 + kh] = f2b(v.z);
            sWt[(4 * j + 3) * 48 + kh] = f2b(v.w);
        }
        __syncthreads();

        // ---- GEMM2: accC += H(128x32) . W2chunk(32x192) ----
        s8v aH0 = *(const s8v*)(sH + (wv * 16 + lr) * 40 + g * 8);
        s8v aH1 = *(const s8v*)(sH + (wv * 16 + 64 + lr) * 40 + g * 8);
        #pragma unroll
        for (int nt = 0; nt < 12; ++nt) {
            s8v bW = *(const s8v*)(sWt + (nt * 16 + lr) * 48 + g * 8);
            accC[0][nt] = __builtin_amdgcn_mfma_f32_16x16x32_bf16(aH0, bW, accC[0][nt], 0, 0, 0);
            accC[1][nt] = __builtin_amdgcn_mfma_f32_16x16x32_bf16(aH1, bW, accC[1][nt], 0, 0, 0);
        }
    }

    // ---- epilogue: out = x + accC + b2 (in place, f32) ----
    #pragma unroll
    for (int mi = 0; mi < 2; ++mi)
        #pragma unroll
        for (int nt = 0; nt < 12; ++nt) {
            int col = nt * 16 + lr;
            float bb = b2[col];
            #pragma unroll
            for (int e = 0; e < 4; ++e) {
                int row = rowbase + wv * 16 + mi * 64 + g * 4 + e;
                float* p = xio + row * 192 + col;
                *p = accC[mi][nt][e] + bb + *p;
            }
        }
}

extern "C" void kernel_launch(void* const* d_in, const int* in_sizes, int n_in,
                              void* d_out, int out_size, void* d_ws, size_t ws_size,
                              hipStream_t stream) {
    const float* skip   = (const float*)d_in[0];
    const float* xup    = (const float*)d_in[1];
    const float* g1     = (const float*)d_in[2];
    const float* be1    = (const float*)d_in[3];
    const float* g2     = (const float*)d_in[4];
    const float* be2    = (const float*)d_in[5];
    const float* Wkv    = (const float*)d_in[6];
    const float* bkv    = (const float*)d_in[7];
    const float* Wproj  = (const float*)d_in[8];
    const float* bproj  = (const float*)d_in[9];
    const float* btab   = (const float*)d_in[10];
    const int*  relidx  = (const int*)d_in[11];
    const float* W1     = (const float*)d_in[12];
    const float* b1     = (const float*)d_in[13];
    const float* W2     = (const float*)d_in[14];
    const float* b2     = (const float*)d_in[15];
    float* xio = (float*)d_out;   // x lives in d_out; k_mlp updates it in place

    k_attn<<<4096, 256, 0, stream>>>(skip, xup, g1, be1, Wkv, bkv, Wproj, bproj, btab, relidx, xio);
    k_mlp<<<2048, 256, 0, stream>>>(xio, g2, be2, W1, b1, W2, b2);
}

// Round 6
// 1464.659 us; speedup vs baseline: 4.8303x; 2.8972x over previous
//
#include <hip/hip_runtime.h>
#include <hip/hip_bf16.h>

typedef __hip_bfloat16 bf16;
typedef short s8v __attribute__((ext_vector_type(8)));   // 8 bf16 (4 VGPRs)
typedef float f32x4 __attribute__((ext_vector_type(4)));

__device__ __forceinline__ float b2f(bf16 v) { return __bfloat162float(v); }
__device__ __forceinline__ bf16 f2b(float v) { return __float2bfloat16(v); }

union H8 { bf16 h[8]; s8v v; uint2 u2[2]; };

__device__ __forceinline__ float gelu_f(float v) {
    // exact-gelu via Abramowitz-Stegun 7.1.26 erf (|eps| <= 1.5e-7)
    float z = fabsf(v) * 0.70710678118654752f;
    float t = 1.f / (1.f + 0.3275911f * z);
    float poly = t * (0.254829592f + t * (-0.284496736f + t * (1.421413741f +
                 t * (-1.453152027f + t * 1.061405429f))));
    float erfz = 1.f - poly * __expf(-z * z);
    erfz = copysignf(erfz, v);
    return 0.5f * v * (1.f + erfz);
}

// ---------------------------------------------------------------------------
// Kernel 1 (MFMA): per-window LN1 -> kv -> attention -> proj -> +skip
// grid = 4096 windows, block = 256 (4 waves).  Writes x (f32) to xout (d_out).
// Fragment pattern (verified in k_mlp R5): A row=lane&15, k=(lane>>4)*8+e;
// B col=lane&15, same k, read from [n][k]-transposed LDS; C/D col=lane&15,
// row=(lane>>4)*4+reg.
// ---------------------------------------------------------------------------
__global__ __launch_bounds__(256, 2) void k_attn(
    const float* __restrict__ skip, const float* __restrict__ xup,
    const float* __restrict__ g1,   const float* __restrict__ be1,
    const float* __restrict__ Wkv,  const float* __restrict__ bkv,
    const float* __restrict__ Wproj,const float* __restrict__ bproj,
    const float* __restrict__ btab, const int*  __restrict__ relidx,
    float* __restrict__ xout)
{
    __shared__ __align__(16) bf16 sK[64 * 200];      // K tokens x C      (25600 B)
    __shared__ __align__(16) char poolRaw[36864];    // {sVt[192][72] + sP[64][72]} then sO[64][200]
    __shared__ __align__(16) char wtRaw[19200];      // sWt[48][200] / sRel[4096]

    bf16* sVt = (bf16*)poolRaw;                // [192][72]  V^T: d x token
    bf16* sP  = (bf16*)(poolRaw + 27648);      // [64][72]   P per head
    bf16* sO  = (bf16*)poolRaw;                // [64][200]  after attention
    bf16* sWt = (bf16*)wtRaw;                  // [48][200]  weight chunk, [n][k]
    int*  sRel= (int*)wtRaw;                   // [4096]

    const int tid = threadIdx.x;
    const int lane = tid & 63;
    const int wv = tid >> 6;
    const int g = lane >> 4;        // k-group
    const int lr = lane & 15;       // A-row / B-col within 16-tile
    const int w = blockIdx.x;
    const int b = w >> 11;
    const int widx = w & 2047;
    const int d0 = widx >> 8, h0 = (widx >> 4) & 15, w0 = widx & 15;

    // token t (0..63) -> global row index
    #define GROW(t) (b * 131072 + (d0 * 4 + ((t) >> 4)) * 4096 + \
                     (h0 * 4 + (((t) >> 2) & 3)) * 64 + (w0 * 4 + ((t) & 3)))

    // ================= Phase A: load + LN1 in registers =================
    const int myrow = wv * 16 + lr;
    const int growA = GROW(myrow) * 192;
    float4 u4[12], s4[12];
    #pragma unroll
    for (int ks = 0; ks < 6; ++ks) {
        int k0 = 32 * ks + 8 * g;
        u4[2 * ks]     = *(const float4*)(xup  + growA + k0);
        u4[2 * ks + 1] = *(const float4*)(xup  + growA + k0 + 4);
        s4[2 * ks]     = *(const float4*)(skip + growA + k0);
        s4[2 * ks + 1] = *(const float4*)(skip + growA + k0 + 4);
    }
    float su = 0, squ = 0, ss = 0, sqs = 0;
    #pragma unroll
    for (int i = 0; i < 12; ++i) {
        const float* up = &u4[i].x;
        const float* sp = &s4[i].x;
        #pragma unroll
        for (int e = 0; e < 4; ++e) {
            su += up[e]; squ += up[e] * up[e];
            ss += sp[e]; sqs += sp[e] * sp[e];
        }
    }
    su += __shfl_xor(su, 16);  su += __shfl_xor(su, 32);
    squ += __shfl_xor(squ, 16); squ += __shfl_xor(squ, 32);
    ss += __shfl_xor(ss, 16);  ss += __shfl_xor(ss, 32);
    sqs += __shfl_xor(sqs, 16); sqs += __shfl_xor(sqs, 32);
    const float inv192 = 1.f / 192.f;
    float muU = su * inv192, vU = squ * inv192 - muU * muU;
    float muS = ss * inv192, vS = sqs * inv192 - muS * muS;
    float rU = rsqrtf(vU + 1e-5f), rS = rsqrtf(vS + 1e-5f);
    const float scale = 0.17677669529663687f;   // 32^-0.5 (folded into Q)

    s8v qreg[6], sreg[6];
    #pragma unroll
    for (int ks = 0; ks < 6; ++ks) {
        H8 qa, sa;
        #pragma unroll
        for (int half = 0; half < 2; ++half) {
            const float* up = &u4[2 * ks + half].x;
            const float* sp = &s4[2 * ks + half].x;
            #pragma unroll
            for (int e = 0; e < 4; ++e) {
                int k = 32 * ks + 8 * g + 4 * half + e;
                float gg = g1[k], bb = be1[k];
                qa.h[4 * half + e] = f2b(((up[e] - muU) * rU * gg + bb) * scale);
                sa.h[4 * half + e] = f2b((sp[e] - muS) * rS * gg + bb);
            }
        }
        qreg[ks] = qa.v; sreg[ks] = sa.v;
    }

    // ================= Phase B: kv GEMM (8 N-chunks of 48) =================
    for (int nc = 0; nc < 8; ++nc) {
        __syncthreads();          // prev chunk's sWt reads done
        #pragma unroll
        for (int i = 0; i < 9; ++i) {
            int ci = tid + i * 256;              // 2304 float4s: 192k x 12j
            int k = ci / 12, j = ci % 12;
            float4 v = *(const float4*)(Wkv + k * 384 + nc * 48 + 4 * j);
            sWt[(4 * j + 0) * 200 + k] = f2b(v.x);
            sWt[(4 * j + 1) * 200 + k] = f2b(v.y);
            sWt[(4 * j + 2) * 200 + k] = f2b(v.z);
            sWt[(4 * j + 3) * 200 + k] = f2b(v.w);
        }
        __syncthreads();

        f32x4 acc[3];
        #pragma unroll
        for (int nt = 0; nt < 3; ++nt) acc[nt] = (f32x4){0.f, 0.f, 0.f, 0.f};
        #pragma unroll
        for (int ks = 0; ks < 6; ++ks) {
            #pragma unroll
            for (int nt = 0; nt < 3; ++nt) {
                s8v bfr = *(const s8v*)(sWt + (nt * 16 + lr) * 200 + 32 * ks + 8 * g);
                acc[nt] = __builtin_amdgcn_mfma_f32_16x16x32_bf16(sreg[ks], bfr, acc[nt], 0, 0, 0);
            }
        }
        if (nc < 4) {             // K columns (c < 192)
            #pragma unroll
            for (int nt = 0; nt < 3; ++nt) {
                int c = nc * 48 + nt * 16 + lr;
                float bias = bkv[c];
                #pragma unroll
                for (int e = 0; e < 4; ++e)
                    sK[(wv * 16 + 4 * g + e) * 200 + c] = f2b(acc[nt][e] + bias);
            }
        } else {                  // V columns -> transposed sVt[d][token]
            #pragma unroll
            for (int nt = 0; nt < 3; ++nt) {
                int c = nc * 48 + nt * 16 + lr;
                float bias = bkv[c];
                int d = c - 192;
                H8 t4;
                #pragma unroll
                for (int e = 0; e < 4; ++e) t4.h[e] = f2b(acc[nt][e] + bias);
                *(uint2*)(sVt + d * 72 + wv * 16 + 4 * g) = t4.u2[0];
            }
        }
    }
    __syncthreads();

    // stage relidx into sWt region (dead until proj)
    #pragma unroll
    for (int i = 0; i < 16; ++i) sRel[tid + i * 256] = relidx[tid + i * 256];
    __syncthreads();
    int bidx[4][4];
    #pragma unroll
    for (int nt = 0; nt < 4; ++nt)
        #pragma unroll
        for (int e = 0; e < 4; ++e)
            bidx[nt][e] = sRel[(wv * 16 + 4 * g + e) * 64 + nt * 16 + lr] * 6;

    // ================= Phase C: attention per head =================
    f32x4 accO[6][2];
    #pragma unroll
    for (int h = 0; h < 6; ++h)
        #pragma unroll
        for (int nt = 0; nt < 2; ++nt) accO[h][nt] = (f32x4){0.f, 0.f, 0.f, 0.f};

    #pragma unroll
    for (int h = 0; h < 6; ++h) {
        // QK^T: wave's 16 q-rows x 64 kt  (K=32 -> 1 MFMA per 16x16 tile)
        f32x4 s[4];
        #pragma unroll
        for (int nt = 0; nt < 4; ++nt) {
            s8v kf = *(const s8v*)(sK + (nt * 16 + lr) * 200 + h * 32 + 8 * g);
            s[nt] = __builtin_amdgcn_mfma_f32_16x16x32_bf16(qreg[h], kf,
                        (f32x4){0.f, 0.f, 0.f, 0.f}, 0, 0, 0);
        }
        // + relative-position bias
        #pragma unroll
        for (int nt = 0; nt < 4; ++nt)
            #pragma unroll
            for (int e = 0; e < 4; ++e)
                s[nt][e] += btab[bidx[nt][e] + h];
        // softmax over kt (4 regs x 16 lr-lanes) per q-row e
        float mx0 = fmaxf(fmaxf(s[0][0], s[1][0]), fmaxf(s[2][0], s[3][0]));
        float mx1 = fmaxf(fmaxf(s[0][1], s[1][1]), fmaxf(s[2][1], s[3][1]));
        float mx2 = fmaxf(fmaxf(s[0][2], s[1][2]), fmaxf(s[2][2], s[3][2]));
        float mx3 = fmaxf(fmaxf(s[0][3], s[1][3]), fmaxf(s[2][3], s[3][3]));
        #pragma unroll
        for (int m = 1; m <= 8; m <<= 1) {
            mx0 = fmaxf(mx0, __shfl_xor(mx0, m));
            mx1 = fmaxf(mx1, __shfl_xor(mx1, m));
            mx2 = fmaxf(mx2, __shfl_xor(mx2, m));
            mx3 = fmaxf(mx3, __shfl_xor(mx3, m));
        }
        float sm0 = 0, sm1 = 0, sm2 = 0, sm3 = 0;
        #pragma unroll
        for (int nt = 0; nt < 4; ++nt) {
            s[nt][0] = __expf(s[nt][0] - mx0); sm0 += s[nt][0];
            s[nt][1] = __expf(s[nt][1] - mx1); sm1 += s[nt][1];
            s[nt][2] = __expf(s[nt][2] - mx2); sm2 += s[nt][2];
            s[nt][3] = __expf(s[nt][3] - mx3); sm3 += s[nt][3];
        }
        #pragma unroll
        for (int m = 1; m <= 8; m <<= 1) {
            sm0 += __shfl_xor(sm0, m); sm1 += __shfl_xor(sm1, m);
            sm2 += __shfl_xor(sm2, m); sm3 += __shfl_xor(sm3, m);
        }
        float iv0 = 1.f / sm0, iv1 = 1.f / sm1, iv2 = 1.f / sm2, iv3 = 1.f / sm3;

        __syncthreads();   // previous head's sP reads done
        #pragma unroll
        for (int nt = 0; nt < 4; ++nt) {
            int kt = nt * 16 + lr;
            sP[(wv * 16 + 4 * g + 0) * 72 + kt] = f2b(s[nt][0] * iv0);
            sP[(wv * 16 + 4 * g + 1) * 72 + kt] = f2b(s[nt][1] * iv1);
            sP[(wv * 16 + 4 * g + 2) * 72 + kt] = f2b(s[nt][2] * iv2);
            sP[(wv * 16 + 4 * g + 3) * 72 + kt] = f2b(s[nt][3] * iv3);
        }
        __syncthreads();

        // PV: O[q][d] += P[q][t] V[t][d];  A from sP rows, B from sVt rows
        s8v aP0 = *(const s8v*)(sP + (wv * 16 + lr) * 72 + 8 * g);
        s8v aP1 = *(const s8v*)(sP + (wv * 16 + lr) * 72 + 32 + 8 * g);
        #pragma unroll
        for (int nt = 0; nt < 2; ++nt) {
            const bf16* vb = sVt + (h * 32 + nt * 16 + lr) * 72;
            s8v v0 = *(const s8v*)(vb + 8 * g);
            s8v v1 = *(const s8v*)(vb + 32 + 8 * g);
            accO[h][nt] = __builtin_amdgcn_mfma_f32_16x16x32_bf16(aP0, v0, accO[h][nt], 0, 0, 0);
            accO[h][nt] = __builtin_amdgcn_mfma_f32_16x16x32_bf16(aP1, v1, accO[h][nt], 0, 0, 0);
        }
    }

    // ---- spill O to LDS (sVt/sP dead -> sO aliases them) ----
    __syncthreads();
    #pragma unroll
    for (int h = 0; h < 6; ++h)
        #pragma unroll
        for (int nt = 0; nt < 2; ++nt) {
            int c = h * 32 + nt * 16 + lr;
            #pragma unroll
            for (int e = 0; e < 4; ++e)
                sO[(wv * 16 + 4 * g + e) * 200 + c] = f2b(accO[h][nt][e]);
        }
    __syncthreads();
    s8v aO[6];
    #pragma unroll
    for (int ks = 0; ks < 6; ++ks)
        aO[ks] = *(const s8v*)(sO + (wv * 16 + lr) * 200 + 32 * ks + 8 * g);

    // ================= Phase D: proj (4 N-chunks of 48) + residual =================
    int gq[4];
    #pragma unroll
    for (int e = 0; e < 4; ++e) gq[e] = GROW(wv * 16 + 4 * g + e) * 192;

    for (int nc = 0; nc < 4; ++nc) {
        __syncthreads();
        #pragma unroll
        for (int i = 0; i < 9; ++i) {
            int ci = tid + i * 256;              // 2304 float4s: 192k x 12j
            int k = ci / 12, j = ci % 12;
            float4 v = *(const float4*)(Wproj + k * 192 + nc * 48 + 4 * j);
            sWt[(4 * j + 0) * 200 + k] = f2b(v.x);
            sWt[(4 * j + 1) * 200 + k] = f2b(v.y);
            sWt[(4 * j + 2) * 200 + k] = f2b(v.z);
            sWt[(4 * j + 3) * 200 + k] = f2b(v.w);
        }
        __syncthreads();

        f32x4 acc[3];
        #pragma unroll
        for (int nt = 0; nt < 3; ++nt) acc[nt] = (f32x4){0.f, 0.f, 0.f, 0.f};
        #pragma unroll
        for (int ks = 0; ks < 6; ++ks) {
            #pragma unroll
            for (int nt = 0; nt < 3; ++nt) {
                s8v bfr = *(const s8v*)(sWt + (nt * 16 + lr) * 200 + 32 * ks + 8 * g);
                acc[nt] = __builtin_amdgcn_mfma_f32_16x16x32_bf16(aO[ks], bfr, acc[nt], 0, 0, 0);
            }
        }
        #pragma unroll
        for (int nt = 0; nt < 3; ++nt) {
            int c = nc * 48 + nt * 16 + lr;
            float bp = bproj[c];
            #pragma unroll
            for (int e = 0; e < 4; ++e) {
                int go = gq[e] + c;
                xout[go] = acc[nt][e] + bp + skip[go];
            }
        }
    }
    #undef GROW
}

// ---------------------------------------------------------------------------
// Kernel 2 (unchanged, passing since R5): out = x + MLP(LN2(x)), in place.
// grid = 2048 (128 rows/block), block = 256 (4 waves).
// ---------------------------------------------------------------------------
__global__ __launch_bounds__(256, 2) void k_mlp(
    float* __restrict__ xio,
    const float* __restrict__ g2, const float* __restrict__ be2,
    const float* __restrict__ W1, const float* __restrict__ b1,
    const float* __restrict__ W2, const float* __restrict__ b2)
{
    __shared__ __align__(16) bf16 sX[128 * 200];
    __shared__ __align__(16) bf16 sH[128 * 40];
    __shared__ __align__(16) bf16 sWt[9216];

    const int tid = threadIdx.x;
    const int lane = tid & 63;
    const int wv = tid >> 6;
    const int g = lane >> 4;
    const int lr = lane & 15;
    const int rowbase = blockIdx.x * 128;

    for (int i = 0; i < 24; ++i) {
        int ci = tid + i * 256;
        int r = ci / 48, j = ci % 48;
        float4 v = *(const float4*)(xio + (rowbase + r) * 192 + 4 * j);
        bf16 t4[4] = {f2b(v.x), f2b(v.y), f2b(v.z), f2b(v.w)};
        *(uint2*)(sX + r * 200 + 4 * j) = *(uint2*)t4;
    }
    __syncthreads();
    {
        int r = tid >> 1, sub = tid & 1;
        int cb = sub * 96;
        float s = 0, sq = 0;
        for (int j = 0; j < 24; ++j) {
            int c = cb + 4 * j;
            uint2 u = *(uint2*)(sX + r * 200 + c);
            const bf16* p = (const bf16*)&u;
            #pragma unroll
            for (int e = 0; e < 4; ++e) { float v = b2f(p[e]); s += v; sq += v * v; }
        }
        s += __shfl_xor(s, 1); sq += __shfl_xor(sq, 1);
        float mu = s * (1.f / 192.f), var = sq * (1.f / 192.f) - mu * mu;
        float rs = rsqrtf(var + 1e-5f);
        for (int j = 0; j < 24; ++j) {
            int c = cb + 4 * j;
            uint2 u = *(uint2*)(sX + r * 200 + c);
            const bf16* p = (const bf16*)&u;
            float4 gg = *(const float4*)(g2 + c);
            float4 be = *(const float4*)(be2 + c);
            bf16 t4[4] = { f2b((b2f(p[0]) - mu) * rs * gg.x + be.x),
                           f2b((b2f(p[1]) - mu) * rs * gg.y + be.y),
                           f2b((b2f(p[2]) - mu) * rs * gg.z + be.z),
                           f2b((b2f(p[3]) - mu) * rs * gg.w + be.w) };
            *(uint2*)(sX + r * 200 + c) = *(uint2*)t4;
        }
    }

    f32x4 accC[2][12];
    #pragma unroll
    for (int mi = 0; mi < 2; ++mi)
        #pragma unroll
        for (int nt = 0; nt < 12; ++nt) accC[mi][nt] = (f32x4){0.f, 0.f, 0.f, 0.f};

    for (int ch = 0; ch < 24; ++ch) {
        int n0 = ch * 32;
        __syncthreads();
        for (int i = 0; i < 6; ++i) {
            int ci = tid + i * 256;
            int k = ci >> 3, j = ci & 7;
            float4 v = *(const float4*)(W1 + k * 768 + n0 + 4 * j);
            sWt[(4 * j + 0) * 200 + k] = f2b(v.x);
            sWt[(4 * j + 1) * 200 + k] = f2b(v.y);
            sWt[(4 * j + 2) * 200 + k] = f2b(v.z);
            sWt[(4 * j + 3) * 200 + k] = f2b(v.w);
        }
        __syncthreads();

        f32x4 accH[2][2];
        #pragma unroll
        for (int mi = 0; mi < 2; ++mi)
            #pragma unroll
            for (int nt = 0; nt < 2; ++nt) accH[mi][nt] = (f32x4){0.f, 0.f, 0.f, 0.f};

        #pragma unroll
        for (int ks = 0; ks < 6; ++ks) {
            s8v a0 = *(const s8v*)(sX + (wv * 16 + lr) * 200 + ks * 32 + g * 8);
            s8v a1 = *(const s8v*)(sX + (wv * 16 + 64 + lr) * 200 + ks * 32 + g * 8);
            s8v b0 = *(const s8v*)(sWt + lr * 200 + ks * 32 + g * 8);
            s8v b1f = *(const s8v*)(sWt + (16 + lr) * 200 + ks * 32 + g * 8);
            accH[0][0] = __builtin_amdgcn_mfma_f32_16x16x32_bf16(a0, b0,  accH[0][0], 0, 0, 0);
            accH[0][1] = __builtin_amdgcn_mfma_f32_16x16x32_bf16(a0, b1f, accH[0][1], 0, 0, 0);
            accH[1][0] = __builtin_amdgcn_mfma_f32_16x16x32_bf16(a1, b0,  accH[1][0], 0, 0, 0);
            accH[1][1] = __builtin_amdgcn_mfma_f32_16x16x32_bf16(a1, b1f, accH[1][1], 0, 0, 0);
        }

        #pragma unroll
        for (int mi = 0; mi < 2; ++mi)
            #pragma unroll
            for (int nt = 0; nt < 2; ++nt) {
                float bb = b1[n0 + nt * 16 + lr];
                #pragma unroll
                for (int e = 0; e < 4; ++e) {
                    int row = wv * 16 + mi * 64 + g * 4 + e;
                    int hc = nt * 16 + lr;
                    sH[row * 40 + hc] = f2b(gelu_f(accH[mi][nt][e] + bb));
                }
            }
        __syncthreads();

        for (int i = 0; i < 6; ++i) {
            int ci = tid + i * 256;
            int kh = ci / 48, j = ci % 48;
            float4 v = *(const float4*)(W2 + (n0 + kh) * 192 + 4 * j);
            sWt[(4 * j + 0) * 48 + kh] = f2b(v.x);
            sWt[(4 * j + 1) * 48 + kh] = f2b(v.y);
            sWt[(4 * j + 2) * 48 + kh] = f2b(v.z);
            sWt[(4 * j + 3) * 48 + kh] = f2b(v.w);
        }
        __syncthreads();

        s8v aH0 = *(const s8v*)(sH + (wv * 16 + lr) * 40 + g * 8);
        s8v aH1 = *(const s8v*)(sH + (wv * 16 + 64 + lr) * 40 + g * 8);
        #pragma unroll
        for (int nt = 0; nt < 12; ++nt) {
            s8v bW = *(const s8v*)(sWt + (nt * 16 + lr) * 48 + g * 8);
            accC[0][nt] = __builtin_amdgcn_mfma_f32_16x16x32_bf16(aH0, bW, accC[0][nt], 0, 0, 0);
            accC[1][nt] = __builtin_amdgcn_mfma_f32_16x16x32_bf16(aH1, bW, accC[1][nt], 0, 0, 0);
        }
    }

    #pragma unroll
    for (int mi = 0; mi < 2; ++mi)
        #pragma unroll
        for (int nt = 0; nt < 12; ++nt) {
            int col = nt * 16 + lr;
            float bb = b2[col];
            #pragma unroll
            for (int e = 0; e < 4; ++e) {
                int row = rowbase + wv * 16 + mi * 64 + g * 4 + e;
                float* p = xio + row * 192 + col;
                *p = accC[mi][nt][e] + bb + *p;
            }
        }
}

extern "C" void kernel_launch(void* const* d_in, const int* in_sizes, int n_in,
                              void* d_out, int out_size, void* d_ws, size_t ws_size,
                              hipStream_t stream) {
    const float* skip   = (const float*)d_in[0];
    const float* xup    = (const float*)d_in[1];
    const float* g1     = (const float*)d_in[2];
    const float* be1    = (const float*)d_in[3];
    const float* g2     = (const float*)d_in[4];
    const float* be2    = (const float*)d_in[5];
    const float* Wkv    = (const float*)d_in[6];
    const float* bkv    = (const float*)d_in[7];
    const float* Wproj  = (const float*)d_in[8];
    const float* bproj  = (const float*)d_in[9];
    const float* btab   = (const float*)d_in[10];
    const int*  relidx  = (const int*)d_in[11];
    const float* W1     = (const float*)d_in[12];
    const float* b1     = (const float*)d_in[13];
    const float* W2     = (const float*)d_in[14];
    const float* b2     = (const float*)d_in[15];
    float* xio = (float*)d_out;   // x lives in d_out; k_mlp updates it in place

    k_attn<<<4096, 256, 0, stream>>>(skip, xup, g1, be1, Wkv, bkv, Wproj, bproj, btab, relidx, xio);
    k_mlp<<<2048, 256, 0, stream>>>(xio, g2, be2, W1, b1, W2, b2);
}

// Round 7
// 612.060 us; speedup vs baseline: 11.5588x; 2.3930x over previous
//
#include <hip/hip_runtime.h>
#include <hip/hip_bf16.h>

typedef __hip_bfloat16 bf16;
typedef short s8v __attribute__((ext_vector_type(8)));   // 8 bf16 (4 VGPRs)
typedef float f32x4 __attribute__((ext_vector_type(4)));

__device__ __forceinline__ float b2f(bf16 v) { return __bfloat162float(v); }
__device__ __forceinline__ bf16 f2b(float v) { return __float2bfloat16(v); }

union H8 { bf16 h[8]; s8v v; uint2 u2[2]; };

__device__ __forceinline__ float gelu_f(float v) {
    // exact-gelu via Abramowitz-Stegun 7.1.26 erf (|eps| <= 1.5e-7)
    float z = fabsf(v) * 0.70710678118654752f;
    float t = 1.f / (1.f + 0.3275911f * z);
    float poly = t * (0.254829592f + t * (-0.284496736f + t * (1.421413741f +
                 t * (-1.453152027f + t * 1.061405429f))));
    float erfz = 1.f - poly * __expf(-z * z);
    erfz = copysignf(erfz, v);
    return 0.5f * v * (1.f + erfz);
}

// async stage: copy nseg*1024B of fragment-linear image into LDS (linear dest)
__device__ __forceinline__ void stage_frag(const bf16* __restrict__ img, bf16* lds,
                                           int nseg, int wv, int lane) {
    for (int seg = wv; seg < nseg; seg += 4) {
        __builtin_amdgcn_global_load_lds(
            (const __attribute__((address_space(1))) void*)(img + seg * 512 + (lane << 3)),
            (__attribute__((address_space(3))) void*)(lds + seg * 512),
            16, 0, 0);
    }
}

// ---------------------------------------------------------------------------
// k_prep: build fragment-linear bf16 weight images in ws.
//   imgKv : [8 chunks][18 tiles(ks*3+nt)][64 lanes][8]   (73728 elems)
//   imgPr : [4 chunks][18 tiles(ks*3+nt)][64 lanes][8]   (36864, base 73728)
//   imgMlp: [24 chunks][ W1:12 tiles(ks*2+nt2) | W2:12 tiles(nt) ][64][8]
//           (294912, base 110592; 12288 elems per chunk)
// frag(lane,e) = W[k + e][n], k = tileK + (lane>>4)*8, n = tileN + (lane&15)
// ---------------------------------------------------------------------------
__global__ __launch_bounds__(256) void k_prep(
    const float* __restrict__ Wkv, const float* __restrict__ Wproj,
    const float* __restrict__ W1,  const float* __restrict__ W2,
    bf16* __restrict__ ws)
{
    int t = blockIdx.x * 256 + threadIdx.x;
    if (t >= 50688) return;
    int k, n, ld;
    const float* W;
    bf16* dst;
    if (t < 9216) {                 // Wkv
        int c = t / 1152, r = t % 1152;
        int tile = r >> 6, lane = r & 63;
        int ks = tile / 3, nt = tile % 3;
        n = c * 48 + nt * 16 + (lane & 15);
        k = ks * 32 + (lane >> 4) * 8;
        W = Wkv; ld = 384; dst = ws + t * 8;
    } else if (t < 13824) {         // Wproj
        int t2 = t - 9216;
        int c = t2 / 1152, r = t2 % 1152;
        int tile = r >> 6, lane = r & 63;
        int ks = tile / 3, nt = tile % 3;
        n = c * 48 + nt * 16 + (lane & 15);
        k = ks * 32 + (lane >> 4) * 8;
        W = Wproj; ld = 192; dst = ws + 73728 + t2 * 8;
    } else {                        // W1 / W2
        int t3 = t - 13824;
        int c = t3 / 1536, r = t3 % 1536;
        int half = r / 768, rr = r % 768;
        int tile = rr >> 6, lane = rr & 63;
        int lr = lane & 15, g = lane >> 4;
        if (half == 0) {            // W1[k][n0+n]
            int ks = tile >> 1, nt2 = tile & 1;
            n = c * 32 + nt2 * 16 + lr; k = ks * 32 + g * 8; W = W1; ld = 768;
        } else {                    // W2[n0+k][n]
            n = tile * 16 + lr; k = c * 32 + g * 8; W = W2; ld = 192;
        }
        dst = ws + 110592 + t3 * 8;
    }
    #pragma unroll
    for (int e = 0; e < 8; ++e) dst[e] = f2b(W[(k + e) * ld + n]);
}

// ---------------------------------------------------------------------------
// Kernel 1 (MFMA): per-window LN1 -> kv -> attention -> proj -> +skip
// grid = 4096 windows, block = 256 (4 waves).  Writes x (f32) to xout (d_out).
// ---------------------------------------------------------------------------
__global__ __launch_bounds__(256, 2) void k_attn(
    const float* __restrict__ skip, const float* __restrict__ xup,
    const float* __restrict__ g1,   const float* __restrict__ be1,
    const bf16*  __restrict__ imgKv,const float* __restrict__ bkv,
    const bf16*  __restrict__ imgPr,const float* __restrict__ bproj,
    const float* __restrict__ btab, const int*  __restrict__ relidx,
    float* __restrict__ xout)
{
    __shared__ __align__(16) bf16 sK[64 * 200];      // 25600 B
    __shared__ __align__(16) char poolRaw[36864];    // {sVt[192][72] + sP[64][72]} then sO[64][200]
    __shared__ __align__(1024) bf16 sWt[9216];       // 18432 B fragment-linear chunk

    bf16* sVt = (bf16*)poolRaw;                // [192][72]  V^T: d x token
    bf16* sP  = (bf16*)(poolRaw + 27648);      // [64][72]   P per head
    bf16* sO  = (bf16*)poolRaw;                // [64][200]  after attention

    const int tid = threadIdx.x;
    const int lane = tid & 63;
    const int wv = tid >> 6;
    const int g = lane >> 4;        // k-group
    const int lr = lane & 15;       // A-row / B-col within 16-tile
    const int w = blockIdx.x;
    const int b = w >> 11;
    const int widx = w & 2047;
    const int d0 = widx >> 8, h0 = (widx >> 4) & 15, w0 = widx & 15;

    #define GROW(t) (b * 131072 + (d0 * 4 + ((t) >> 4)) * 4096 + \
                     (h0 * 4 + (((t) >> 2) & 3)) * 64 + (w0 * 4 + ((t) & 3)))

    // ================= Phase A: load + LN1 in registers =================
    const int myrow = wv * 16 + lr;
    const int growA = GROW(myrow) * 192;
    float4 u4[12], s4[12];
    #pragma unroll
    for (int ks = 0; ks < 6; ++ks) {
        int k0 = 32 * ks + 8 * g;
        u4[2 * ks]     = *(const float4*)(xup  + growA + k0);
        u4[2 * ks + 1] = *(const float4*)(xup  + growA + k0 + 4);
        s4[2 * ks]     = *(const float4*)(skip + growA + k0);
        s4[2 * ks + 1] = *(const float4*)(skip + growA + k0 + 4);
    }
    float su = 0, squ = 0, ss = 0, sqs = 0;
    #pragma unroll
    for (int i = 0; i < 12; ++i) {
        const float* up = &u4[i].x;
        const float* sp = &s4[i].x;
        #pragma unroll
        for (int e = 0; e < 4; ++e) {
            su += up[e]; squ += up[e] * up[e];
            ss += sp[e]; sqs += sp[e] * sp[e];
        }
    }
    su += __shfl_xor(su, 16);  su += __shfl_xor(su, 32);
    squ += __shfl_xor(squ, 16); squ += __shfl_xor(squ, 32);
    ss += __shfl_xor(ss, 16);  ss += __shfl_xor(ss, 32);
    sqs += __shfl_xor(sqs, 16); sqs += __shfl_xor(sqs, 32);
    const float inv192 = 1.f / 192.f;
    float muU = su * inv192, vU = squ * inv192 - muU * muU;
    float muS = ss * inv192, vS = sqs * inv192 - muS * muS;
    float rU = rsqrtf(vU + 1e-5f), rS = rsqrtf(vS + 1e-5f);
    const float scale = 0.17677669529663687f;   // 32^-0.5 (folded into Q)

    s8v qreg[6], sreg[6];
    #pragma unroll
    for (int ks = 0; ks < 6; ++ks) {
        H8 qa, sa;
        #pragma unroll
        for (int half = 0; half < 2; ++half) {
            const float* up = &u4[2 * ks + half].x;
            const float* sp = &s4[2 * ks + half].x;
            #pragma unroll
            for (int e = 0; e < 4; ++e) {
                int k = 32 * ks + 8 * g + 4 * half + e;
                float gg = g1[k], bb = be1[k];
                qa.h[4 * half + e] = f2b(((up[e] - muU) * rU * gg + bb) * scale);
                sa.h[4 * half + e] = f2b((sp[e] - muS) * rS * gg + bb);
            }
        }
        qreg[ks] = qa.v; sreg[ks] = sa.v;
    }

    // ================= Phase B: kv GEMM (8 N-chunks of 48) =================
    for (int nc = 0; nc < 8; ++nc) {
        __syncthreads();                              // prev chunk's sWt reads done
        stage_frag(imgKv + nc * 9216, sWt, 18, wv, lane);
        __syncthreads();                              // staged (implicit vmcnt(0) drain)

        f32x4 acc[3];
        #pragma unroll
        for (int nt = 0; nt < 3; ++nt) acc[nt] = (f32x4){0.f, 0.f, 0.f, 0.f};
        #pragma unroll
        for (int ks = 0; ks < 6; ++ks) {
            #pragma unroll
            for (int nt = 0; nt < 3; ++nt) {
                s8v bfr = *(const s8v*)(sWt + ((ks * 3 + nt) * 64 + lane) * 8);
                acc[nt] = __builtin_amdgcn_mfma_f32_16x16x32_bf16(sreg[ks], bfr, acc[nt], 0, 0, 0);
            }
        }
        if (nc < 4) {             // K columns (c < 192)
            #pragma unroll
            for (int nt = 0; nt < 3; ++nt) {
                int c = nc * 48 + nt * 16 + lr;
                float bias = bkv[c];
                #pragma unroll
                for (int e = 0; e < 4; ++e)
                    sK[(wv * 16 + 4 * g + e) * 200 + c] = f2b(acc[nt][e] + bias);
            }
        } else {                  // V columns -> transposed sVt[d][token]
            #pragma unroll
            for (int nt = 0; nt < 3; ++nt) {
                int c = nc * 48 + nt * 16 + lr;
                float bias = bkv[c];
                int d = c - 192;
                H8 t4;
                #pragma unroll
                for (int e = 0; e < 4; ++e) t4.h[e] = f2b(acc[nt][e] + bias);
                *(uint2*)(sVt + d * 72 + wv * 16 + 4 * g) = t4.u2[0];
            }
        }
    }
    __syncthreads();

    // bias-table indices straight from global (16 KB table, L2-resident)
    int bidx[4][4];
    #pragma unroll
    for (int nt = 0; nt < 4; ++nt)
        #pragma unroll
        for (int e = 0; e < 4; ++e)
            bidx[nt][e] = relidx[(wv * 16 + 4 * g + e) * 64 + nt * 16 + lr] * 6;

    // ================= Phase C: attention per head =================
    f32x4 accO[6][2];
    #pragma unroll
    for (int h = 0; h < 6; ++h)
        #pragma unroll
        for (int nt = 0; nt < 2; ++nt) accO[h][nt] = (f32x4){0.f, 0.f, 0.f, 0.f};

    #pragma unroll
    for (int h = 0; h < 6; ++h) {
        f32x4 s[4];
        #pragma unroll
        for (int nt = 0; nt < 4; ++nt) {
            s8v kf = *(const s8v*)(sK + (nt * 16 + lr) * 200 + h * 32 + 8 * g);
            s[nt] = __builtin_amdgcn_mfma_f32_16x16x32_bf16(qreg[h], kf,
                        (f32x4){0.f, 0.f, 0.f, 0.f}, 0, 0, 0);
        }
        #pragma unroll
        for (int nt = 0; nt < 4; ++nt)
            #pragma unroll
            for (int e = 0; e < 4; ++e)
                s[nt][e] += btab[bidx[nt][e] + h];
        float mx0 = fmaxf(fmaxf(s[0][0], s[1][0]), fmaxf(s[2][0], s[3][0]));
        float mx1 = fmaxf(fmaxf(s[0][1], s[1][1]), fmaxf(s[2][1], s[3][1]));
        float mx2 = fmaxf(fmaxf(s[0][2], s[1][2]), fmaxf(s[2][2], s[3][2]));
        float mx3 = fmaxf(fmaxf(s[0][3], s[1][3]), fmaxf(s[2][3], s[3][3]));
        #pragma unroll
        for (int m = 1; m <= 8; m <<= 1) {
            mx0 = fmaxf(mx0, __shfl_xor(mx0, m));
            mx1 = fmaxf(mx1, __shfl_xor(mx1, m));
            mx2 = fmaxf(mx2, __shfl_xor(mx2, m));
            mx3 = fmaxf(mx3, __shfl_xor(mx3, m));
        }
        float sm0 = 0, sm1 = 0, sm2 = 0, sm3 = 0;
        #pragma unroll
        for (int nt = 0; nt < 4; ++nt) {
            s[nt][0] = __expf(s[nt][0] - mx0); sm0 += s[nt][0];
            s[nt][1] = __expf(s[nt][1] - mx1); sm1 += s[nt][1];
            s[nt][2] = __expf(s[nt][2] - mx2); sm2 += s[nt][2];
            s[nt][3] = __expf(s[nt][3] - mx3); sm3 += s[nt][3];
        }
        #pragma unroll
        for (int m = 1; m <= 8; m <<= 1) {
            sm0 += __shfl_xor(sm0, m); sm1 += __shfl_xor(sm1, m);
            sm2 += __shfl_xor(sm2, m); sm3 += __shfl_xor(sm3, m);
        }
        float iv0 = 1.f / sm0, iv1 = 1.f / sm1, iv2 = 1.f / sm2, iv3 = 1.f / sm3;

        __syncthreads();   // previous head's sP reads done
        #pragma unroll
        for (int nt = 0; nt < 4; ++nt) {
            int kt = nt * 16 + lr;
            sP[(wv * 16 + 4 * g + 0) * 72 + kt] = f2b(s[nt][0] * iv0);
            sP[(wv * 16 + 4 * g + 1) * 72 + kt] = f2b(s[nt][1] * iv1);
            sP[(wv * 16 + 4 * g + 2) * 72 + kt] = f2b(s[nt][2] * iv2);
            sP[(wv * 16 + 4 * g + 3) * 72 + kt] = f2b(s[nt][3] * iv3);
        }
        __syncthreads();

        s8v aP0 = *(const s8v*)(sP + (wv * 16 + lr) * 72 + 8 * g);
        s8v aP1 = *(const s8v*)(sP + (wv * 16 + lr) * 72 + 32 + 8 * g);
        #pragma unroll
        for (int nt = 0; nt < 2; ++nt) {
            const bf16* vb = sVt + (h * 32 + nt * 16 + lr) * 72;
            s8v v0 = *(const s8v*)(vb + 8 * g);
            s8v v1 = *(const s8v*)(vb + 32 + 8 * g);
            accO[h][nt] = __builtin_amdgcn_mfma_f32_16x16x32_bf16(aP0, v0, accO[h][nt], 0, 0, 0);
            accO[h][nt] = __builtin_amdgcn_mfma_f32_16x16x32_bf16(aP1, v1, accO[h][nt], 0, 0, 0);
        }
    }

    // ---- spill O to LDS (sVt/sP dead -> sO aliases them) ----
    __syncthreads();
    #pragma unroll
    for (int h = 0; h < 6; ++h)
        #pragma unroll
        for (int nt = 0; nt < 2; ++nt) {
            int c = h * 32 + nt * 16 + lr;
            #pragma unroll
            for (int e = 0; e < 4; ++e)
                sO[(wv * 16 + 4 * g + e) * 200 + c] = f2b(accO[h][nt][e]);
        }
    __syncthreads();
    s8v aO[6];
    #pragma unroll
    for (int ks = 0; ks < 6; ++ks)
        aO[ks] = *(const s8v*)(sO + (wv * 16 + lr) * 200 + 32 * ks + 8 * g);

    // ================= Phase D: proj (4 N-chunks of 48) + residual =================
    int gq[4];
    #pragma unroll
    for (int e = 0; e < 4; ++e) gq[e] = GROW(wv * 16 + 4 * g + e) * 192;

    for (int nc = 0; nc < 4; ++nc) {
        __syncthreads();
        stage_frag(imgPr + nc * 9216, sWt, 18, wv, lane);
        __syncthreads();

        f32x4 acc[3];
        #pragma unroll
        for (int nt = 0; nt < 3; ++nt) acc[nt] = (f32x4){0.f, 0.f, 0.f, 0.f};
        #pragma unroll
        for (int ks = 0; ks < 6; ++ks) {
            #pragma unroll
            for (int nt = 0; nt < 3; ++nt) {
                s8v bfr = *(const s8v*)(sWt + ((ks * 3 + nt) * 64 + lane) * 8);
                acc[nt] = __builtin_amdgcn_mfma_f32_16x16x32_bf16(aO[ks], bfr, acc[nt], 0, 0, 0);
            }
        }
        #pragma unroll
        for (int nt = 0; nt < 3; ++nt) {
            int c = nc * 48 + nt * 16 + lr;
            float bp = bproj[c];
            #pragma unroll
            for (int e = 0; e < 4; ++e) {
                int go = gq[e] + c;
                xout[go] = acc[nt][e] + bp + skip[go];
            }
        }
    }
    #undef GROW
}

// ---------------------------------------------------------------------------
// Kernel 2 (MFMA, reg-LN, fragment-linear weights, double-buffered staging):
// out = x + (gelu(LN2(x) @ W1 + b1) @ W2 + b2), in place on d_out.
// grid = 2048 (128 rows/block), block = 256 (4 waves).
// ---------------------------------------------------------------------------
__global__ __launch_bounds__(256, 2) void k_mlp(
    float* __restrict__ xio,
    const float* __restrict__ g2, const float* __restrict__ be2,
    const bf16*  __restrict__ imgMlp,
    const float* __restrict__ b1, const float* __restrict__ b2)
{
    __shared__ __align__(1024) bf16 sW[2][12288];   // 2 x 24576 B chunk images
    __shared__ __align__(16) bf16 sH[128 * 40];     // hidden chunk, rows padded to 40

    const int tid = threadIdx.x;
    const int lane = tid & 63;
    const int wv = tid >> 6;
    const int g = lane >> 4;
    const int lr = lane & 15;
    const int rowbase = blockIdx.x * 128;

    // stage chunk 0 early; x-load + LN2 hide its latency
    stage_frag(imgMlp, sW[0], 24, wv, lane);

    // ---- x load + LN2 entirely in registers (rows wv*16+mi*64+lr) ----
    s8v xreg[2][6];
    #pragma unroll
    for (int mi = 0; mi < 2; ++mi) {
        const int row = rowbase + wv * 16 + mi * 64 + lr;
        float4 xa[12];
        #pragma unroll
        for (int ks = 0; ks < 6; ++ks) {
            int k0 = 32 * ks + 8 * g;
            xa[2 * ks]     = *(const float4*)(xio + row * 192 + k0);
            xa[2 * ks + 1] = *(const float4*)(xio + row * 192 + k0 + 4);
        }
        float s = 0, sq = 0;
        #pragma unroll
        for (int i = 0; i < 12; ++i) {
            const float* p = &xa[i].x;
            #pragma unroll
            for (int e = 0; e < 4; ++e) { s += p[e]; sq += p[e] * p[e]; }
        }
        s += __shfl_xor(s, 16);  s += __shfl_xor(s, 32);
        sq += __shfl_xor(sq, 16); sq += __shfl_xor(sq, 32);
        float mu = s * (1.f / 192.f), var = sq * (1.f / 192.f) - mu * mu;
        float rs = rsqrtf(var + 1e-5f);
        #pragma unroll
        for (int ks = 0; ks < 6; ++ks) {
            H8 xa8;
            #pragma unroll
            for (int half = 0; half < 2; ++half) {
                int k0 = 32 * ks + 8 * g + 4 * half;
                float4 gg = *(const float4*)(g2 + k0);
                float4 be = *(const float4*)(be2 + k0);
                const float* p = &xa[2 * ks + half].x;
                const float* gp = &gg.x;
                const float* bp = &be.x;
                #pragma unroll
                for (int e = 0; e < 4; ++e)
                    xa8.h[4 * half + e] = f2b((p[e] - mu) * rs * gp[e] + bp[e]);
            }
            xreg[mi][ks] = xa8.v;
        }
    }

    f32x4 accC[2][12];
    #pragma unroll
    for (int mi = 0; mi < 2; ++mi)
        #pragma unroll
        for (int nt = 0; nt < 12; ++nt) accC[mi][nt] = (f32x4){0.f, 0.f, 0.f, 0.f};

    for (int ch = 0; ch < 24; ++ch) {
        const int c = ch & 1;
        __syncthreads();    // sW[c] staged (implicit vmcnt(0)); prev GEMM reads of sW[c^1] done
        if (ch < 23) stage_frag(imgMlp + (ch + 1) * 12288, sW[c ^ 1], 24, wv, lane);
        const bf16* wc = sW[c];

        // ---- GEMM1: accH = X(128x192) . W1chunk(192x32) ----
        f32x4 accH[2][2];
        #pragma unroll
        for (int mi = 0; mi < 2; ++mi)
            #pragma unroll
            for (int nt = 0; nt < 2; ++nt) accH[mi][nt] = (f32x4){0.f, 0.f, 0.f, 0.f};
        #pragma unroll
        for (int ks = 0; ks < 6; ++ks) {
            s8v b0  = *(const s8v*)(wc + ((ks * 2 + 0) * 64 + lane) * 8);
            s8v b1f = *(const s8v*)(wc + ((ks * 2 + 1) * 64 + lane) * 8);
            accH[0][0] = __builtin_amdgcn_mfma_f32_16x16x32_bf16(xreg[0][ks], b0,  accH[0][0], 0, 0, 0);
            accH[0][1] = __builtin_amdgcn_mfma_f32_16x16x32_bf16(xreg[0][ks], b1f, accH[0][1], 0, 0, 0);
            accH[1][0] = __builtin_amdgcn_mfma_f32_16x16x32_bf16(xreg[1][ks], b0,  accH[1][0], 0, 0, 0);
            accH[1][1] = __builtin_amdgcn_mfma_f32_16x16x32_bf16(xreg[1][ks], b1f, accH[1][1], 0, 0, 0);
        }

        // ---- gelu + store H chunk ----
        #pragma unroll
        for (int mi = 0; mi < 2; ++mi)
            #pragma unroll
            for (int nt = 0; nt < 2; ++nt) {
                float bb = b1[ch * 32 + nt * 16 + lr];
                #pragma unroll
                for (int e = 0; e < 4; ++e) {
                    int row = wv * 16 + mi * 64 + g * 4 + e;
                    sH[row * 40 + nt * 16 + lr] = f2b(gelu_f(accH[mi][nt][e] + bb));
                }
            }
        __syncthreads();    // sH ready

        // ---- GEMM2: accC += H(128x32) . W2chunk(32x192) ----
        s8v aH0 = *(const s8v*)(sH + (wv * 16 + lr) * 40 + g * 8);
        s8v aH1 = *(const s8v*)(sH + (wv * 16 + 64 + lr) * 40 + g * 8);
        #pragma unroll
        for (int nt = 0; nt < 12; ++nt) {
            s8v bW = *(const s8v*)(wc + 6144 + (nt * 64 + lane) * 8);
            accC[0][nt] = __builtin_amdgcn_mfma_f32_16x16x32_bf16(aH0, bW, accC[0][nt], 0, 0, 0);
            accC[1][nt] = __builtin_amdgcn_mfma_f32_16x16x32_bf16(aH1, bW, accC[1][nt], 0, 0, 0);
        }
    }

    // ---- epilogue: out = x + accC + b2 (in place, f32) ----
    #pragma unroll
    for (int mi = 0; mi < 2; ++mi)
        #pragma unroll
        for (int nt = 0; nt < 12; ++nt) {
            int col = nt * 16 + lr;
            float bb = b2[col];
            #pragma unroll
            for (int e = 0; e < 4; ++e) {
                int row = rowbase + wv * 16 + mi * 64 + g * 4 + e;
                float* p = xio + row * 192 + col;
                *p = accC[mi][nt][e] + bb + *p;
            }
        }
}

extern "C" void kernel_launch(void* const* d_in, const int* in_sizes, int n_in,
                              void* d_out, int out_size, void* d_ws, size_t ws_size,
                              hipStream_t stream) {
    const float* skip   = (const float*)d_in[0];
    const float* xup    = (const float*)d_in[1];
    const float* g1     = (const float*)d_in[2];
    const float* be1    = (const float*)d_in[3];
    const float* g2     = (const float*)d_in[4];
    const float* be2    = (const float*)d_in[5];
    const float* Wkv    = (const float*)d_in[6];
    const float* bkv    = (const float*)d_in[7];
    const float* Wproj  = (const float*)d_in[8];
    const float* bproj  = (const float*)d_in[9];
    const float* btab   = (const float*)d_in[10];
    const int*  relidx  = (const int*)d_in[11];
    const float* W1     = (const float*)d_in[12];
    const float* b1     = (const float*)d_in[13];
    const float* W2     = (const float*)d_in[14];
    const float* b2     = (const float*)d_in[15];
    float* xio = (float*)d_out;          // x lives in d_out; k_mlp updates it in place
    bf16* ws = (bf16*)d_ws;              // weight images (~811 KB)

    k_prep<<<198, 256, 0, stream>>>(Wkv, Wproj, W1, W2, ws);
    k_attn<<<4096, 256, 0, stream>>>(skip, xup, g1, be1, ws, bkv,
                                     ws + 73728, bproj, btab, relidx, xio);
    k_mlp<<<2048, 256, 0, stream>>>(xio, g2, be2, ws + 110592, b1, b2);
}

// Round 8
// 586.637 us; speedup vs baseline: 12.0597x; 1.0433x over previous
//
#include <hip/hip_runtime.h>
#include <hip/hip_bf16.h>

typedef __hip_bfloat16 bf16;
typedef short s8v __attribute__((ext_vector_type(8)));   // 8 bf16 (4 VGPRs)
typedef float f32x4 __attribute__((ext_vector_type(4)));

__device__ __forceinline__ float b2f(bf16 v) { return __bfloat162float(v); }
__device__ __forceinline__ bf16 f2b(float v) { return __float2bfloat16(v); }

union H8 { bf16 h[8]; s8v v; uint2 u2[2]; };

__device__ __forceinline__ float gelu_f(float v) {
    // exact-gelu via Abramowitz-Stegun 7.1.26 erf (|eps| <= 1.5e-7)
    float z = fabsf(v) * 0.70710678118654752f;
    float t = 1.f / (1.f + 0.3275911f * z);
    float poly = t * (0.254829592f + t * (-0.284496736f + t * (1.421413741f +
                 t * (-1.453152027f + t * 1.061405429f))));
    float erfz = 1.f - poly * __expf(-z * z);
    erfz = copysignf(erfz, v);
    return 0.5f * v * (1.f + erfz);
}

// async stage: copy nseg*1024B of fragment-linear image into LDS (linear dest)
__device__ __forceinline__ void stage_frag(const bf16* __restrict__ img, bf16* lds,
                                           int nseg, int wv, int lane) {
    for (int seg = wv; seg < nseg; seg += 4) {
        __builtin_amdgcn_global_load_lds(
            (const __attribute__((address_space(1))) void*)(img + seg * 512 + (lane << 3)),
            (__attribute__((address_space(3))) void*)(lds + seg * 512),
            16, 0, 0);
    }
}

// ---------------------------------------------------------------------------
// k_prep: build fragment-linear bf16 weight images in ws (unchanged from R7).
// frag(lane,e) = W[k + e][n], k = tileK + (lane>>4)*8, n = tileN + (lane&15)
// ---------------------------------------------------------------------------
__global__ __launch_bounds__(256) void k_prep(
    const float* __restrict__ Wkv, const float* __restrict__ Wproj,
    const float* __restrict__ W1,  const float* __restrict__ W2,
    bf16* __restrict__ ws)
{
    int t = blockIdx.x * 256 + threadIdx.x;
    if (t >= 50688) return;
    int k, n, ld;
    const float* W;
    bf16* dst;
    if (t < 9216) {                 // Wkv
        int c = t / 1152, r = t % 1152;
        int tile = r >> 6, lane = r & 63;
        int ks = tile / 3, nt = tile % 3;
        n = c * 48 + nt * 16 + (lane & 15);
        k = ks * 32 + (lane >> 4) * 8;
        W = Wkv; ld = 384; dst = ws + t * 8;
    } else if (t < 13824) {         // Wproj
        int t2 = t - 9216;
        int c = t2 / 1152, r = t2 % 1152;
        int tile = r >> 6, lane = r & 63;
        int ks = tile / 3, nt = tile % 3;
        n = c * 48 + nt * 16 + (lane & 15);
        k = ks * 32 + (lane >> 4) * 8;
        W = Wproj; ld = 192; dst = ws + 73728 + t2 * 8;
    } else {                        // W1 / W2
        int t3 = t - 13824;
        int c = t3 / 1536, r = t3 % 1536;
        int half = r / 768, rr = r % 768;
        int tile = rr >> 6, lane = rr & 63;
        int lr = lane & 15, g = lane >> 4;
        if (half == 0) {            // W1[k][n0+n]
            int ks = tile >> 1, nt2 = tile & 1;
            n = c * 32 + nt2 * 16 + lr; k = ks * 32 + g * 8; W = W1; ld = 768;
        } else {                    // W2[n0+k][n]
            n = tile * 16 + lr; k = c * 32 + g * 8; W = W2; ld = 192;
        }
        dst = ws + 110592 + t3 * 8;
    }
    #pragma unroll
    for (int e = 0; e < 8; ++e) dst[e] = f2b(W[(k + e) * ld + n]);
}

// ---------------------------------------------------------------------------
// Kernel 1 (MFMA, swapped QK/PV): per-window LN1 -> kv -> attn -> proj -> +skip
// grid = 4096 windows, block = 256 (4 waves).  Writes x (f32) to xout (d_out).
// ---------------------------------------------------------------------------
__global__ __launch_bounds__(256, 2) void k_attn(
    const float* __restrict__ skip, const float* __restrict__ xup,
    const float* __restrict__ g1,   const float* __restrict__ be1,
    const bf16*  __restrict__ imgKv,const float* __restrict__ bkv,
    const bf16*  __restrict__ imgPr,const float* __restrict__ bproj,
    const float* __restrict__ btab, const int*  __restrict__ relidx,
    float* __restrict__ xout)
{
    __shared__ __align__(16) bf16 sK[64 * 200];      // 25600 B
    __shared__ __align__(16) char poolRaw[36864];    // {sVt[192][72] + sP[64][72]} then sO[64][200]
    __shared__ __align__(1024) bf16 sWt[9216];       // weight chunk / f32 bias table

    bf16* sVt = (bf16*)poolRaw;                // [192][72]  V^T: d x token
    bf16* sP  = (bf16*)(poolRaw + 27648);      // [64][72]   P per head (wave-private rows)
    bf16* sO  = (bf16*)poolRaw;                // [64][200]  after attention
    float* sBt = (float*)sWt;                  // staged bias table (2058 f32)

    const int tid = threadIdx.x;
    const int lane = tid & 63;
    const int wv = tid >> 6;
    const int g = lane >> 4;        // k-group
    const int lr = lane & 15;       // A-row / B-col within 16-tile
    const int w = blockIdx.x;
    const int b = w >> 11;
    const int widx = w & 2047;
    const int d0 = widx >> 8, h0 = (widx >> 4) & 15, w0 = widx & 15;

    #define GROW(t) (b * 131072 + (d0 * 4 + ((t) >> 4)) * 4096 + \
                     (h0 * 4 + (((t) >> 2) & 3)) * 64 + (w0 * 4 + ((t) & 3)))

    // ================= Phase A: load + LN1 in registers =================
    const int myrow = wv * 16 + lr;
    const int growA = GROW(myrow) * 192;
    float4 u4[12], s4[12];
    #pragma unroll
    for (int ks = 0; ks < 6; ++ks) {
        int k0 = 32 * ks + 8 * g;
        u4[2 * ks]     = *(const float4*)(xup  + growA + k0);
        u4[2 * ks + 1] = *(const float4*)(xup  + growA + k0 + 4);
        s4[2 * ks]     = *(const float4*)(skip + growA + k0);
        s4[2 * ks + 1] = *(const float4*)(skip + growA + k0 + 4);
    }
    float su = 0, squ = 0, ss = 0, sqs = 0;
    #pragma unroll
    for (int i = 0; i < 12; ++i) {
        const float* up = &u4[i].x;
        const float* sp = &s4[i].x;
        #pragma unroll
        for (int e = 0; e < 4; ++e) {
            su += up[e]; squ += up[e] * up[e];
            ss += sp[e]; sqs += sp[e] * sp[e];
        }
    }
    su += __shfl_xor(su, 16);  su += __shfl_xor(su, 32);
    squ += __shfl_xor(squ, 16); squ += __shfl_xor(squ, 32);
    ss += __shfl_xor(ss, 16);  ss += __shfl_xor(ss, 32);
    sqs += __shfl_xor(sqs, 16); sqs += __shfl_xor(sqs, 32);
    const float inv192 = 1.f / 192.f;
    float muU = su * inv192, vU = squ * inv192 - muU * muU;
    float muS = ss * inv192, vS = sqs * inv192 - muS * muS;
    float rU = rsqrtf(vU + 1e-5f), rS = rsqrtf(vS + 1e-5f);
    const float scale = 0.17677669529663687f;   // 32^-0.5 (folded into Q)

    s8v qreg[6], sreg[6];
    #pragma unroll
    for (int ks = 0; ks < 6; ++ks) {
        H8 qa, sa;
        #pragma unroll
        for (int half = 0; half < 2; ++half) {
            const float* up = &u4[2 * ks + half].x;
            const float* sp = &s4[2 * ks + half].x;
            #pragma unroll
            for (int e = 0; e < 4; ++e) {
                int k = 32 * ks + 8 * g + 4 * half + e;
                float gg = g1[k], bb = be1[k];
                qa.h[4 * half + e] = f2b(((up[e] - muU) * rU * gg + bb) * scale);
                sa.h[4 * half + e] = f2b((sp[e] - muS) * rS * gg + bb);
            }
        }
        qreg[ks] = qa.v; sreg[ks] = sa.v;
    }

    // ================= Phase B: kv GEMM (8 N-chunks of 48, unchanged) =================
    for (int nc = 0; nc < 8; ++nc) {
        __syncthreads();
        stage_frag(imgKv + nc * 9216, sWt, 18, wv, lane);
        __syncthreads();

        f32x4 acc[3];
        #pragma unroll
        for (int nt = 0; nt < 3; ++nt) acc[nt] = (f32x4){0.f, 0.f, 0.f, 0.f};
        #pragma unroll
        for (int ks = 0; ks < 6; ++ks) {
            #pragma unroll
            for (int nt = 0; nt < 3; ++nt) {
                s8v bfr = *(const s8v*)(sWt + ((ks * 3 + nt) * 64 + lane) * 8);
                acc[nt] = __builtin_amdgcn_mfma_f32_16x16x32_bf16(sreg[ks], bfr, acc[nt], 0, 0, 0);
            }
        }
        if (nc < 4) {             // K columns -> sK[token][c]
            #pragma unroll
            for (int nt = 0; nt < 3; ++nt) {
                int c = nc * 48 + nt * 16 + lr;
                float bias = bkv[c];
                #pragma unroll
                for (int e = 0; e < 4; ++e)
                    sK[(wv * 16 + 4 * g + e) * 200 + c] = f2b(acc[nt][e] + bias);
            }
        } else {                  // V columns -> transposed sVt[d][token] (packed)
            #pragma unroll
            for (int nt = 0; nt < 3; ++nt) {
                int c = nc * 48 + nt * 16 + lr;
                float bias = bkv[c];
                int d = c - 192;
                H8 t4;
                #pragma unroll
                for (int e = 0; e < 4; ++e) t4.h[e] = f2b(acc[nt][e] + bias);
                *(uint2*)(sVt + d * 72 + wv * 16 + 4 * g) = t4.u2[0];
            }
        }
    }
    __syncthreads();

    // stage bias table (f32) into sWt region; load bias indices (swapped layout)
    for (int i = tid; i < 2058; i += 256) sBt[i] = btab[i];
    int bidx[4][4];
    #pragma unroll
    for (int nt = 0; nt < 4; ++nt)
        #pragma unroll
        for (int e = 0; e < 4; ++e)
            bidx[nt][e] = relidx[(wv * 16 + lr) * 64 + nt * 16 + 4 * g + e] * 6;
    __syncthreads();

    // ================= Phase C: attention per head (swapped, no barriers) ==========
    f32x4 accOT[6][2];
    #pragma unroll
    for (int h = 0; h < 6; ++h)
        #pragma unroll
        for (int nt = 0; nt < 2; ++nt) accOT[h][nt] = (f32x4){0.f, 0.f, 0.f, 0.f};

    #pragma unroll
    for (int h = 0; h < 6; ++h) {
        // S^T = K . Q^T : s[nt][e] = S[qrow=wv*16+lr][kt=nt*16+4g+e]
        f32x4 s[4];
        #pragma unroll
        for (int nt = 0; nt < 4; ++nt) {
            s8v kf = *(const s8v*)(sK + (nt * 16 + lr) * 200 + h * 32 + 8 * g);
            s[nt] = __builtin_amdgcn_mfma_f32_16x16x32_bf16(kf, qreg[h],
                        (f32x4){0.f, 0.f, 0.f, 0.f}, 0, 0, 0);
        }
        #pragma unroll
        for (int nt = 0; nt < 4; ++nt)
            #pragma unroll
            for (int e = 0; e < 4; ++e)
                s[nt][e] += sBt[bidx[nt][e] + h];
        // softmax over kt for this lane's qrow: 16 own values + lanes lr, lr+16, lr+32, lr+48
        float mx = -1e30f;
        #pragma unroll
        for (int nt = 0; nt < 4; ++nt)
            #pragma unroll
            for (int e = 0; e < 4; ++e) mx = fmaxf(mx, s[nt][e]);
        mx = fmaxf(mx, __shfl_xor(mx, 16));
        mx = fmaxf(mx, __shfl_xor(mx, 32));
        float sm = 0;
        #pragma unroll
        for (int nt = 0; nt < 4; ++nt)
            #pragma unroll
            for (int e = 0; e < 4; ++e) { s[nt][e] = __expf(s[nt][e] - mx); sm += s[nt][e]; }
        sm += __shfl_xor(sm, 16);
        sm += __shfl_xor(sm, 32);
        float iv = 1.f / sm;
        // packed P store: sP[qrow][kt], 4 consecutive kt per write (wave-private rows)
        #pragma unroll
        for (int nt = 0; nt < 4; ++nt) {
            H8 pk;
            #pragma unroll
            for (int e = 0; e < 4; ++e) pk.h[e] = f2b(s[nt][e] * iv);
            *(uint2*)(sP + (wv * 16 + lr) * 72 + nt * 16 + 4 * g) = pk.u2[0];
        }
        // O^T = V^T . P^T : accOT[h][ntd] rows d, cols qrow
        s8v aP0 = *(const s8v*)(sP + (wv * 16 + lr) * 72 + 8 * g);
        s8v aP1 = *(const s8v*)(sP + (wv * 16 + lr) * 72 + 32 + 8 * g);
        #pragma unroll
        for (int nt = 0; nt < 2; ++nt) {
            const bf16* vb = sVt + (h * 32 + nt * 16 + lr) * 72;
            s8v v0 = *(const s8v*)(vb + 8 * g);
            s8v v1 = *(const s8v*)(vb + 32 + 8 * g);
            accOT[h][nt] = __builtin_amdgcn_mfma_f32_16x16x32_bf16(v0, aP0, accOT[h][nt], 0, 0, 0);
            accOT[h][nt] = __builtin_amdgcn_mfma_f32_16x16x32_bf16(v1, aP1, accOT[h][nt], 0, 0, 0);
        }
    }

    // ---- spill O (packed): sO[qrow][d]; sVt/sP dead after barrier ----
    __syncthreads();
    #pragma unroll
    for (int h = 0; h < 6; ++h)
        #pragma unroll
        for (int nt = 0; nt < 2; ++nt) {
            H8 pk;
            #pragma unroll
            for (int e = 0; e < 4; ++e) pk.h[e] = f2b(accOT[h][nt][e]);
            *(uint2*)(sO + (wv * 16 + lr) * 200 + h * 32 + nt * 16 + 4 * g) = pk.u2[0];
        }
    s8v aO[6];
    #pragma unroll
    for (int ks = 0; ks < 6; ++ks)
        aO[ks] = *(const s8v*)(sO + (wv * 16 + lr) * 200 + 32 * ks + 8 * g);

    // ================= Phase D: proj (4 N-chunks of 48) + residual =================
    int gq[4];
    #pragma unroll
    for (int e = 0; e < 4; ++e) gq[e] = GROW(wv * 16 + 4 * g + e) * 192;

    for (int nc = 0; nc < 4; ++nc) {
        __syncthreads();
        stage_frag(imgPr + nc * 9216, sWt, 18, wv, lane);
        __syncthreads();

        f32x4 acc[3];
        #pragma unroll
        for (int nt = 0; nt < 3; ++nt) acc[nt] = (f32x4){0.f, 0.f, 0.f, 0.f};
        #pragma unroll
        for (int ks = 0; ks < 6; ++ks) {
            #pragma unroll
            for (int nt = 0; nt < 3; ++nt) {
                s8v bfr = *(const s8v*)(sWt + ((ks * 3 + nt) * 64 + lane) * 8);
                acc[nt] = __builtin_amdgcn_mfma_f32_16x16x32_bf16(aO[ks], bfr, acc[nt], 0, 0, 0);
            }
        }
        #pragma unroll
        for (int nt = 0; nt < 3; ++nt) {
            int c = nc * 48 + nt * 16 + lr;
            float bp = bproj[c];
            #pragma unroll
            for (int e = 0; e < 4; ++e) {
                int go = gq[e] + c;
                xout[go] = acc[nt][e] + bp + skip[go];
            }
        }
    }
    #undef GROW
}

// ---------------------------------------------------------------------------
// Kernel 2 (MFMA, swapped GEMM1, 1 barrier/chunk): out = x + MLP(LN2(x)).
// grid = 2048 (128 rows/block), block = 256 (4 waves).  In place on d_out.
// ---------------------------------------------------------------------------
__global__ __launch_bounds__(256, 2) void k_mlp(
    float* __restrict__ xio,
    const float* __restrict__ g2, const float* __restrict__ be2,
    const bf16*  __restrict__ imgMlp,
    const float* __restrict__ b1, const float* __restrict__ b2)
{
    __shared__ __align__(1024) bf16 sW[2][12288];   // 2 x 24576 B chunk images
    __shared__ __align__(16) bf16 sH[128 * 40];     // hidden chunk (wave-private rows)

    const int tid = threadIdx.x;
    const int lane = tid & 63;
    const int wv = tid >> 6;
    const int g = lane >> 4;
    const int lr = lane & 15;
    const int rowbase = blockIdx.x * 128;

    // stage chunk 0 early; x-load + LN2 hide its latency
    stage_frag(imgMlp, sW[0], 24, wv, lane);

    // ---- x load + LN2 entirely in registers (rows wv*16+mi*64+lr) ----
    s8v xreg[2][6];
    #pragma unroll
    for (int mi = 0; mi < 2; ++mi) {
        const int row = rowbase + wv * 16 + mi * 64 + lr;
        float4 xa[12];
        #pragma unroll
        for (int ks = 0; ks < 6; ++ks) {
            int k0 = 32 * ks + 8 * g;
            xa[2 * ks]     = *(const float4*)(xio + row * 192 + k0);
            xa[2 * ks + 1] = *(const float4*)(xio + row * 192 + k0 + 4);
        }
        float s = 0, sq = 0;
        #pragma unroll
        for (int i = 0; i < 12; ++i) {
            const float* p = &xa[i].x;
            #pragma unroll
            for (int e = 0; e < 4; ++e) { s += p[e]; sq += p[e] * p[e]; }
        }
        s += __shfl_xor(s, 16);  s += __shfl_xor(s, 32);
        sq += __shfl_xor(sq, 16); sq += __shfl_xor(sq, 32);
        float mu = s * (1.f / 192.f), var = sq * (1.f / 192.f) - mu * mu;
        float rs = rsqrtf(var + 1e-5f);
        #pragma unroll
        for (int ks = 0; ks < 6; ++ks) {
            H8 xa8;
            #pragma unroll
            for (int half = 0; half < 2; ++half) {
                int k0 = 32 * ks + 8 * g + 4 * half;
                float4 gg = *(const float4*)(g2 + k0);
                float4 be = *(const float4*)(be2 + k0);
                const float* p = &xa[2 * ks + half].x;
                const float* gp = &gg.x;
                const float* bp = &be.x;
                #pragma unroll
                for (int e = 0; e < 4; ++e)
                    xa8.h[4 * half + e] = f2b((p[e] - mu) * rs * gp[e] + bp[e]);
            }
            xreg[mi][ks] = xa8.v;
        }
    }

    f32x4 accC[2][12];
    #pragma unroll
    for (int mi = 0; mi < 2; ++mi)
        #pragma unroll
        for (int nt = 0; nt < 12; ++nt) accC[mi][nt] = (f32x4){0.f, 0.f, 0.f, 0.f};

    for (int ch = 0; ch < 24; ++ch) {
        const int c = ch & 1;
        __syncthreads();    // sW[c] staged (vmcnt drained); prev reads of sW[c^1] done
        if (ch < 23) stage_frag(imgMlp + (ch + 1) * 12288, sW[c ^ 1], 24, wv, lane);
        const bf16* wc = sW[c];

        // ---- GEMM1 swapped: H^T = W1c^T . X^T  (hid = 4g+e, xrow = lr) ----
        f32x4 accHT[2][2];
        #pragma unroll
        for (int mi = 0; mi < 2; ++mi)
            #pragma unroll
            for (int nt = 0; nt < 2; ++nt) accHT[mi][nt] = (f32x4){0.f, 0.f, 0.f, 0.f};
        #pragma unroll
        for (int ks = 0; ks < 6; ++ks) {
            s8v w0 = *(const s8v*)(wc + ((ks * 2 + 0) * 64 + lane) * 8);
            s8v w1 = *(const s8v*)(wc + ((ks * 2 + 1) * 64 + lane) * 8);
            accHT[0][0] = __builtin_amdgcn_mfma_f32_16x16x32_bf16(w0, xreg[0][ks], accHT[0][0], 0, 0, 0);
            accHT[0][1] = __builtin_amdgcn_mfma_f32_16x16x32_bf16(w1, xreg[0][ks], accHT[0][1], 0, 0, 0);
            accHT[1][0] = __builtin_amdgcn_mfma_f32_16x16x32_bf16(w0, xreg[1][ks], accHT[1][0], 0, 0, 0);
            accHT[1][1] = __builtin_amdgcn_mfma_f32_16x16x32_bf16(w1, xreg[1][ks], accHT[1][1], 0, 0, 0);
        }

        // ---- gelu + packed H store (wave-private rows; no barrier) ----
        #pragma unroll
        for (int mi = 0; mi < 2; ++mi)
            #pragma unroll
            for (int nt2 = 0; nt2 < 2; ++nt2) {
                float4 b1v = *(const float4*)(b1 + ch * 32 + nt2 * 16 + 4 * g);
                const float* bp = &b1v.x;
                H8 pk;
                #pragma unroll
                for (int e = 0; e < 4; ++e)
                    pk.h[e] = f2b(gelu_f(accHT[mi][nt2][e] + bp[e]));
                *(uint2*)(sH + (wv * 16 + mi * 64 + lr) * 40 + nt2 * 16 + 4 * g) = pk.u2[0];
            }

        // ---- GEMM2: accC += H(128x32) . W2chunk(32x192) ----
        s8v aH0 = *(const s8v*)(sH + (wv * 16 + lr) * 40 + g * 8);
        s8v aH1 = *(const s8v*)(sH + (wv * 16 + 64 + lr) * 40 + g * 8);
        #pragma unroll
        for (int nt = 0; nt < 12; ++nt) {
            s8v bW = *(const s8v*)(wc + 6144 + (nt * 64 + lane) * 8);
            accC[0][nt] = __builtin_amdgcn_mfma_f32_16x16x32_bf16(aH0, bW, accC[0][nt], 0, 0, 0);
            accC[1][nt] = __builtin_amdgcn_mfma_f32_16x16x32_bf16(aH1, bW, accC[1][nt], 0, 0, 0);
        }
    }

    // ---- epilogue: out = x + accC + b2 (in place, f32) ----
    #pragma unroll
    for (int mi = 0; mi < 2; ++mi)
        #pragma unroll
        for (int nt = 0; nt < 12; ++nt) {
            int col = nt * 16 + lr;
            float bb = b2[col];
            #pragma unroll
            for (int e = 0; e < 4; ++e) {
                int row = rowbase + wv * 16 + mi * 64 + g * 4 + e;
                float* p = xio + row * 192 + col;
                *p = accC[mi][nt][e] + bb + *p;
            }
        }
}

extern "C" void kernel_launch(void* const* d_in, const int* in_sizes, int n_in,
                              void* d_out, int out_size, void* d_ws, size_t ws_size,
                              hipStream_t stream) {
    const float* skip   = (const float*)d_in[0];
    const float* xup    = (const float*)d_in[1];
    const float* g1     = (const float*)d_in[2];
    const float* be1    = (const float*)d_in[3];
    const float* g2     = (const float*)d_in[4];
    const float* be2    = (const float*)d_in[5];
    const float* Wkv    = (const float*)d_in[6];
    const float* bkv    = (const float*)d_in[7];
    const float* Wproj  = (const float*)d_in[8];
    const float* bproj  = (const float*)d_in[9];
    const float* btab   = (const float*)d_in[10];
    const int*  relidx  = (const int*)d_in[11];
    const float* W1     = (const float*)d_in[12];
    const float* b1     = (const float*)d_in[13];
    const float* W2     = (const float*)d_in[14];
    const float* b2     = (const float*)d_in[15];
    float* xio = (float*)d_out;          // x lives in d_out; k_mlp updates it in place
    bf16* ws = (bf16*)d_ws;              // weight images (~811 KB)

    k_prep<<<198, 256, 0, stream>>>(Wkv, Wproj, W1, W2, ws);
    k_attn<<<4096, 256, 0, stream>>>(skip, xup, g1, be1, ws, bkv,
                                     ws + 73728, bproj, btab, relidx, xio);
    k_mlp<<<2048, 256, 0, stream>>>(xio, g2, be2, ws + 110592, b1, b2);
}

// Round 9
// 585.653 us; speedup vs baseline: 12.0800x; 1.0017x over previous
//
#include <hip/hip_runtime.h>
#include <hip/hip_bf16.h>

typedef __hip_bfloat16 bf16;
typedef short s8v __attribute__((ext_vector_type(8)));   // 8 bf16 (4 VGPRs)
typedef float f32x4 __attribute__((ext_vector_type(4)));

__device__ __forceinline__ float b2f(bf16 v) { return __bfloat162float(v); }
__device__ __forceinline__ bf16 f2b(float v) { return __float2bfloat16(v); }

union H8 { bf16 h[8]; s8v v; uint2 u2[2]; };

// tanh-approx gelu in sigmoid form: 0.5x(1+tanh(y)) == x*sigmoid(2y)
// max |err| vs exact-erf gelu ~1e-3 -> negligible through W2 (~0.02-scale).
__device__ __forceinline__ float gelu_f(float x) {
    float x2 = x * x;
    float t = fmaf(x2, 0.044715f, 1.0f);
    float u = x * 1.5957691216057308f * t;     // 2 * 0.7978845608 * x * t
    float e = __expf(-u);
    return x / (1.0f + e);
}

// async stage: copy nseg*1024B of fragment-linear image into LDS (linear dest)
__device__ __forceinline__ void stage_frag(const bf16* __restrict__ img, bf16* lds,
                                           int nseg, int wv, int lane) {
    for (int seg = wv; seg < nseg; seg += 4) {
        __builtin_amdgcn_global_load_lds(
            (const __attribute__((address_space(1))) void*)(img + seg * 512 + (lane << 3)),
            (__attribute__((address_space(3))) void*)(lds + seg * 512),
            16, 0, 0);
    }
}

// ---------------------------------------------------------------------------
// k_prep: build fragment-linear bf16 weight images in ws (unchanged).
// frag(lane,e) = W[k + e][n], k = tileK + (lane>>4)*8, n = tileN + (lane&15)
// ---------------------------------------------------------------------------
__global__ __launch_bounds__(256) void k_prep(
    const float* __restrict__ Wkv, const float* __restrict__ Wproj,
    const float* __restrict__ W1,  const float* __restrict__ W2,
    bf16* __restrict__ ws)
{
    int t = blockIdx.x * 256 + threadIdx.x;
    if (t >= 50688) return;
    int k, n, ld;
    const float* W;
    bf16* dst;
    if (t < 9216) {                 // Wkv
        int c = t / 1152, r = t % 1152;
        int tile = r >> 6, lane = r & 63;
        int ks = tile / 3, nt = tile % 3;
        n = c * 48 + nt * 16 + (lane & 15);
        k = ks * 32 + (lane >> 4) * 8;
        W = Wkv; ld = 384; dst = ws + t * 8;
    } else if (t < 13824) {         // Wproj
        int t2 = t - 9216;
        int c = t2 / 1152, r = t2 % 1152;
        int tile = r >> 6, lane = r & 63;
        int ks = tile / 3, nt = tile % 3;
        n = c * 48 + nt * 16 + (lane & 15);
        k = ks * 32 + (lane >> 4) * 8;
        W = Wproj; ld = 192; dst = ws + 73728 + t2 * 8;
    } else {                        // W1 / W2
        int t3 = t - 13824;
        int c = t3 / 1536, r = t3 % 1536;
        int half = r / 768, rr = r % 768;
        int tile = rr >> 6, lane = rr & 63;
        int lr = lane & 15, g = lane >> 4;
        if (half == 0) {            // W1[k][n0+n]
            int ks = tile >> 1, nt2 = tile & 1;
            n = c * 32 + nt2 * 16 + lr; k = ks * 32 + g * 8; W = W1; ld = 768;
        } else {                    // W2[n0+k][n]
            n = tile * 16 + lr; k = c * 32 + g * 8; W = W2; ld = 192;
        }
        dst = ws + 110592 + t3 * 8;
    }
    #pragma unroll
    for (int e = 0; e < 8; ++e) dst[e] = f2b(W[(k + e) * ld + n]);
}

// ---------------------------------------------------------------------------
// Kernel 1 (MFMA, reg B-frags, 2 barriers total): LN1 -> kv -> attn -> proj
// grid = 4096 windows, block = 256 (4 waves).  Writes x (f32) to xout (d_out).
// ---------------------------------------------------------------------------
__global__ __launch_bounds__(256, 2) void k_attn(
    const float* __restrict__ skip, const float* __restrict__ xup,
    const float* __restrict__ g1,   const float* __restrict__ be1,
    const bf16*  __restrict__ imgKv,const float* __restrict__ bkv,
    const bf16*  __restrict__ imgPr,const float* __restrict__ bproj,
    const float* __restrict__ btab, const int*  __restrict__ relidx,
    float* __restrict__ xout)
{
    __shared__ __align__(16) bf16 sK[64 * 200];      // 25600 B
    __shared__ __align__(16) char poolRaw[36864];    // {sVt[192][72] + sP[64][72]} then sO[64][200]
    __shared__ __align__(16) float sBt[2058];        // staged bias table (8232 B)

    bf16* sVt = (bf16*)poolRaw;                // [192][72]  V^T: d x token
    bf16* sP  = (bf16*)(poolRaw + 27648);      // [64][72]   P per head (wave-private rows)
    bf16* sO  = (bf16*)poolRaw;                // [64][200]  after attention

    const int tid = threadIdx.x;
    const int lane = tid & 63;
    const int wv = tid >> 6;
    const int g = lane >> 4;        // k-group
    const int lr = lane & 15;       // A-row / B-col within 16-tile
    const int w = blockIdx.x;
    const int b = w >> 11;
    const int widx = w & 2047;
    const int d0 = widx >> 8, h0 = (widx >> 4) & 15, w0 = widx & 15;

    #define GROW(t) (b * 131072 + (d0 * 4 + ((t) >> 4)) * 4096 + \
                     (h0 * 4 + (((t) >> 2) & 3)) * 64 + (w0 * 4 + ((t) & 3)))

    // ================= Phase A: load + LN1 in registers =================
    const int myrow = wv * 16 + lr;
    const int growA = GROW(myrow) * 192;
    float4 u4[12], s4[12];
    #pragma unroll
    for (int ks = 0; ks < 6; ++ks) {
        int k0 = 32 * ks + 8 * g;
        u4[2 * ks]     = *(const float4*)(xup  + growA + k0);
        u4[2 * ks + 1] = *(const float4*)(xup  + growA + k0 + 4);
        s4[2 * ks]     = *(const float4*)(skip + growA + k0);
        s4[2 * ks + 1] = *(const float4*)(skip + growA + k0 + 4);
    }
    float su = 0, squ = 0, ss = 0, sqs = 0;
    #pragma unroll
    for (int i = 0; i < 12; ++i) {
        const float* up = &u4[i].x;
        const float* sp = &s4[i].x;
        #pragma unroll
        for (int e = 0; e < 4; ++e) {
            su += up[e]; squ += up[e] * up[e];
            ss += sp[e]; sqs += sp[e] * sp[e];
        }
    }
    su += __shfl_xor(su, 16);  su += __shfl_xor(su, 32);
    squ += __shfl_xor(squ, 16); squ += __shfl_xor(squ, 32);
    ss += __shfl_xor(ss, 16);  ss += __shfl_xor(ss, 32);
    sqs += __shfl_xor(sqs, 16); sqs += __shfl_xor(sqs, 32);
    const float inv192 = 1.f / 192.f;
    float muU = su * inv192, vU = squ * inv192 - muU * muU;
    float muS = ss * inv192, vS = sqs * inv192 - muS * muS;
    float rU = rsqrtf(vU + 1e-5f), rS = rsqrtf(vS + 1e-5f);
    const float scale = 0.17677669529663687f;   // 32^-0.5 (folded into Q)

    s8v qreg[6], sreg[6];
    #pragma unroll
    for (int ks = 0; ks < 6; ++ks) {
        H8 qa, sa;
        #pragma unroll
        for (int half = 0; half < 2; ++half) {
            const float* up = &u4[2 * ks + half].x;
            const float* sp = &s4[2 * ks + half].x;
            #pragma unroll
            for (int e = 0; e < 4; ++e) {
                int k = 32 * ks + 8 * g + 4 * half + e;
                float gg = g1[k], bb = be1[k];
                qa.h[4 * half + e] = f2b(((up[e] - muU) * rU * gg + bb) * scale);
                sa.h[4 * half + e] = f2b((sp[e] - muS) * rS * gg + bb);
            }
        }
        qreg[ks] = qa.v; sreg[ks] = sa.v;
    }

    // stage bias table into LDS (read after the post-B barrier)
    for (int i = tid; i < 2058; i += 256) sBt[i] = btab[i];

    // ================= Phase B: kv GEMM, B-frags from global (no barriers) ========
    for (int nc = 0; nc < 8; ++nc) {
        const bf16* img = imgKv + nc * 9216;
        f32x4 acc[3];
        #pragma unroll
        for (int nt = 0; nt < 3; ++nt) acc[nt] = (f32x4){0.f, 0.f, 0.f, 0.f};
        #pragma unroll
        for (int ks = 0; ks < 6; ++ks) {
            #pragma unroll
            for (int nt = 0; nt < 3; ++nt) {
                s8v bfr = *(const s8v*)(img + ((ks * 3 + nt) * 64 + lane) * 8);
                acc[nt] = __builtin_amdgcn_mfma_f32_16x16x32_bf16(sreg[ks], bfr, acc[nt], 0, 0, 0);
            }
        }
        if (nc < 4) {             // K columns -> sK[token][c]
            #pragma unroll
            for (int nt = 0; nt < 3; ++nt) {
                int c = nc * 48 + nt * 16 + lr;
                float bias = bkv[c];
                #pragma unroll
                for (int e = 0; e < 4; ++e)
                    sK[(wv * 16 + 4 * g + e) * 200 + c] = f2b(acc[nt][e] + bias);
            }
        } else {                  // V columns -> transposed sVt[d][token] (packed)
            #pragma unroll
            for (int nt = 0; nt < 3; ++nt) {
                int c = nc * 48 + nt * 16 + lr;
                float bias = bkv[c];
                int d = c - 192;
                H8 t4;
                #pragma unroll
                for (int e = 0; e < 4; ++e) t4.h[e] = f2b(acc[nt][e] + bias);
                *(uint2*)(sVt + d * 72 + wv * 16 + 4 * g) = t4.u2[0];
            }
        }
    }

    int bidx[4][4];
    #pragma unroll
    for (int nt = 0; nt < 4; ++nt)
        #pragma unroll
        for (int e = 0; e < 4; ++e)
            bidx[nt][e] = relidx[(wv * 16 + lr) * 64 + nt * 16 + 4 * g + e] * 6;

    __syncthreads();   // BARRIER 1: sK/sVt/sBt visible to all waves

    // ================= Phase C: attention per head (no barriers) =================
    f32x4 accOT[6][2];
    #pragma unroll
    for (int h = 0; h < 6; ++h)
        #pragma unroll
        for (int nt = 0; nt < 2; ++nt) accOT[h][nt] = (f32x4){0.f, 0.f, 0.f, 0.f};

    #pragma unroll
    for (int h = 0; h < 6; ++h) {
        // S^T = K . Q^T : s[nt][e] = S[qrow=wv*16+lr][kt=nt*16+4g+e]
        f32x4 s[4];
        #pragma unroll
        for (int nt = 0; nt < 4; ++nt) {
            s8v kf = *(const s8v*)(sK + (nt * 16 + lr) * 200 + h * 32 + 8 * g);
            s[nt] = __builtin_amdgcn_mfma_f32_16x16x32_bf16(kf, qreg[h],
                        (f32x4){0.f, 0.f, 0.f, 0.f}, 0, 0, 0);
        }
        #pragma unroll
        for (int nt = 0; nt < 4; ++nt)
            #pragma unroll
            for (int e = 0; e < 4; ++e)
                s[nt][e] += sBt[bidx[nt][e] + h];
        // softmax over kt for this lane's qrow (lanes lr, lr+16, lr+32, lr+48)
        float mx = -1e30f;
        #pragma unroll
        for (int nt = 0; nt < 4; ++nt)
            #pragma unroll
            for (int e = 0; e < 4; ++e) mx = fmaxf(mx, s[nt][e]);
        mx = fmaxf(mx, __shfl_xor(mx, 16));
        mx = fmaxf(mx, __shfl_xor(mx, 32));
        float sm = 0;
        #pragma unroll
        for (int nt = 0; nt < 4; ++nt)
            #pragma unroll
            for (int e = 0; e < 4; ++e) { s[nt][e] = __expf(s[nt][e] - mx); sm += s[nt][e]; }
        sm += __shfl_xor(sm, 16);
        sm += __shfl_xor(sm, 32);
        float iv = 1.f / sm;
        // packed P store (wave-private rows)
        #pragma unroll
        for (int nt = 0; nt < 4; ++nt) {
            H8 pk;
            #pragma unroll
            for (int e = 0; e < 4; ++e) pk.h[e] = f2b(s[nt][e] * iv);
            *(uint2*)(sP + (wv * 16 + lr) * 72 + nt * 16 + 4 * g) = pk.u2[0];
        }
        // O^T = V^T . P^T
        s8v aP0 = *(const s8v*)(sP + (wv * 16 + lr) * 72 + 8 * g);
        s8v aP1 = *(const s8v*)(sP + (wv * 16 + lr) * 72 + 32 + 8 * g);
        #pragma unroll
        for (int nt = 0; nt < 2; ++nt) {
            const bf16* vb = sVt + (h * 32 + nt * 16 + lr) * 72;
            s8v v0 = *(const s8v*)(vb + 8 * g);
            s8v v1 = *(const s8v*)(vb + 32 + 8 * g);
            accOT[h][nt] = __builtin_amdgcn_mfma_f32_16x16x32_bf16(v0, aP0, accOT[h][nt], 0, 0, 0);
            accOT[h][nt] = __builtin_amdgcn_mfma_f32_16x16x32_bf16(v1, aP1, accOT[h][nt], 0, 0, 0);
        }
    }

    __syncthreads();   // BARRIER 2: all PV reads of sVt/sP done -> sO may overwrite

    // ---- spill O (packed): sO[qrow][d] ----
    #pragma unroll
    for (int h = 0; h < 6; ++h)
        #pragma unroll
        for (int nt = 0; nt < 2; ++nt) {
            H8 pk;
            #pragma unroll
            for (int e = 0; e < 4; ++e) pk.h[e] = f2b(accOT[h][nt][e]);
            *(uint2*)(sO + (wv * 16 + lr) * 200 + h * 32 + nt * 16 + 4 * g) = pk.u2[0];
        }
    s8v aO[6];
    #pragma unroll
    for (int ks = 0; ks < 6; ++ks)
        aO[ks] = *(const s8v*)(sO + (wv * 16 + lr) * 200 + 32 * ks + 8 * g);

    // ================= Phase D: proj, B-frags from global (no barriers) ==========
    int gq[4];
    #pragma unroll
    for (int e = 0; e < 4; ++e) gq[e] = GROW(wv * 16 + 4 * g + e) * 192;

    for (int nc = 0; nc < 4; ++nc) {
        const bf16* img = imgPr + nc * 9216;
        f32x4 acc[3];
        #pragma unroll
        for (int nt = 0; nt < 3; ++nt) acc[nt] = (f32x4){0.f, 0.f, 0.f, 0.f};
        #pragma unroll
        for (int ks = 0; ks < 6; ++ks) {
            #pragma unroll
            for (int nt = 0; nt < 3; ++nt) {
                s8v bfr = *(const s8v*)(img + ((ks * 3 + nt) * 64 + lane) * 8);
                acc[nt] = __builtin_amdgcn_mfma_f32_16x16x32_bf16(aO[ks], bfr, acc[nt], 0, 0, 0);
            }
        }
        #pragma unroll
        for (int nt = 0; nt < 3; ++nt) {
            int c = nc * 48 + nt * 16 + lr;
            float bp = bproj[c];
            #pragma unroll
            for (int e = 0; e < 4; ++e) {
                int go = gq[e] + c;
                xout[go] = acc[nt][e] + bp + skip[go];
            }
        }
    }
    #undef GROW
}

// ---------------------------------------------------------------------------
// Kernel 2 (MFMA, cheap gelu, single-buffer staging): out = x + MLP(LN2(x)).
// grid = 2048 (128 rows/block), block = 256 (4 waves).  In place on d_out.
// LDS = 34816 B -> up to 4 blocks/CU.
// ---------------------------------------------------------------------------
__global__ __launch_bounds__(256, 2) void k_mlp(
    float* __restrict__ xio,
    const float* __restrict__ g2, const float* __restrict__ be2,
    const bf16*  __restrict__ imgMlp,
    const float* __restrict__ b1, const float* __restrict__ b2)
{
    __shared__ __align__(1024) bf16 sW[12288];      // 24576 B chunk image (single buffer)
    __shared__ __align__(16) bf16 sH[128 * 40];     // hidden chunk (wave-private rows)

    const int tid = threadIdx.x;
    const int lane = tid & 63;
    const int wv = tid >> 6;
    const int g = lane >> 4;
    const int lr = lane & 15;
    const int rowbase = blockIdx.x * 128;

    // ---- x load + LN2 entirely in registers (rows wv*16+mi*64+lr) ----
    s8v xreg[2][6];
    #pragma unroll
    for (int mi = 0; mi < 2; ++mi) {
        const int row = rowbase + wv * 16 + mi * 64 + lr;
        float4 xa[12];
        #pragma unroll
        for (int ks = 0; ks < 6; ++ks) {
            int k0 = 32 * ks + 8 * g;
            xa[2 * ks]     = *(const float4*)(xio + row * 192 + k0);
            xa[2 * ks + 1] = *(const float4*)(xio + row * 192 + k0 + 4);
        }
        float s = 0, sq = 0;
        #pragma unroll
        for (int i = 0; i < 12; ++i) {
            const float* p = &xa[i].x;
            #pragma unroll
            for (int e = 0; e < 4; ++e) { s += p[e]; sq += p[e] * p[e]; }
        }
        s += __shfl_xor(s, 16);  s += __shfl_xor(s, 32);
        sq += __shfl_xor(sq, 16); sq += __shfl_xor(sq, 32);
        float mu = s * (1.f / 192.f), var = sq * (1.f / 192.f) - mu * mu;
        float rs = rsqrtf(var + 1e-5f);
        #pragma unroll
        for (int ks = 0; ks < 6; ++ks) {
            H8 xa8;
            #pragma unroll
            for (int half = 0; half < 2; ++half) {
                int k0 = 32 * ks + 8 * g + 4 * half;
                float4 gg = *(const float4*)(g2 + k0);
                float4 be = *(const float4*)(be2 + k0);
                const float* p = &xa[2 * ks + half].x;
                const float* gp = &gg.x;
                const float* bp = &be.x;
                #pragma unroll
                for (int e = 0; e < 4; ++e)
                    xa8.h[4 * half + e] = f2b((p[e] - mu) * rs * gp[e] + bp[e]);
            }
            xreg[mi][ks] = xa8.v;
        }
    }

    f32x4 accC[2][12];
    #pragma unroll
    for (int mi = 0; mi < 2; ++mi)
        #pragma unroll
        for (int nt = 0; nt < 12; ++nt) accC[mi][nt] = (f32x4){0.f, 0.f, 0.f, 0.f};

    for (int ch = 0; ch < 24; ++ch) {
        __syncthreads();    // prev chunk's sW reads done
        stage_frag(imgMlp + ch * 12288, sW, 24, wv, lane);
        __syncthreads();    // staged (implicit vmcnt(0) drain at barrier)

        // ---- GEMM1 swapped: H^T = W1c^T . X^T  (hid = 4g+e, xrow = lr) ----
        f32x4 accHT[2][2];
        #pragma unroll
        for (int mi = 0; mi < 2; ++mi)
            #pragma unroll
            for (int nt = 0; nt < 2; ++nt) accHT[mi][nt] = (f32x4){0.f, 0.f, 0.f, 0.f};
        #pragma unroll
        for (int ks = 0; ks < 6; ++ks) {
            s8v w0 = *(const s8v*)(sW + ((ks * 2 + 0) * 64 + lane) * 8);
            s8v w1 = *(const s8v*)(sW + ((ks * 2 + 1) * 64 + lane) * 8);
            accHT[0][0] = __builtin_amdgcn_mfma_f32_16x16x32_bf16(w0, xreg[0][ks], accHT[0][0], 0, 0, 0);
            accHT[0][1] = __builtin_amdgcn_mfma_f32_16x16x32_bf16(w1, xreg[0][ks], accHT[0][1], 0, 0, 0);
            accHT[1][0] = __builtin_amdgcn_mfma_f32_16x16x32_bf16(w0, xreg[1][ks], accHT[1][0], 0, 0, 0);
            accHT[1][1] = __builtin_amdgcn_mfma_f32_16x16x32_bf16(w1, xreg[1][ks], accHT[1][1], 0, 0, 0);
        }

        // ---- gelu (cheap) + packed H store (wave-private rows; no barrier) ----
        #pragma unroll
        for (int mi = 0; mi < 2; ++mi)
            #pragma unroll
            for (int nt2 = 0; nt2 < 2; ++nt2) {
                float4 b1v = *(const float4*)(b1 + ch * 32 + nt2 * 16 + 4 * g);
                const float* bp = &b1v.x;
                H8 pk;
                #pragma unroll
                for (int e = 0; e < 4; ++e)
                    pk.h[e] = f2b(gelu_f(accHT[mi][nt2][e] + bp[e]));
                *(uint2*)(sH + (wv * 16 + mi * 64 + lr) * 40 + nt2 * 16 + 4 * g) = pk.u2[0];
            }

        // ---- GEMM2: accC += H(128x32) . W2chunk(32x192) ----
        s8v aH0 = *(const s8v*)(sH + (wv * 16 + lr) * 40 + g * 8);
        s8v aH1 = *(const s8v*)(sH + (wv * 16 + 64 + lr) * 40 + g * 8);
        #pragma unroll
        for (int nt = 0; nt < 12; ++nt) {
            s8v bW = *(const s8v*)(sW + 6144 + (nt * 64 + lane) * 8);
            accC[0][nt] = __builtin_amdgcn_mfma_f32_16x16x32_bf16(aH0, bW, accC[0][nt], 0, 0, 0);
            accC[1][nt] = __builtin_amdgcn_mfma_f32_16x16x32_bf16(aH1, bW, accC[1][nt], 0, 0, 0);
        }
    }

    // ---- epilogue: out = x + accC + b2 (in place, f32) ----
    #pragma unroll
    for (int mi = 0; mi < 2; ++mi)
        #pragma unroll
        for (int nt = 0; nt < 12; ++nt) {
            int col = nt * 16 + lr;
            float bb = b2[col];
            #pragma unroll
            for (int e = 0; e < 4; ++e) {
                int row = rowbase + wv * 16 + mi * 64 + g * 4 + e;
                float* p = xio + row * 192 + col;
                *p = accC[mi][nt][e] + bb + *p;
            }
        }
}

extern "C" void kernel_launch(void* const* d_in, const int* in_sizes, int n_in,
                              void* d_out, int out_size, void* d_ws, size_t ws_size,
                              hipStream_t stream) {
    const float* skip   = (const float*)d_in[0];
    const float* xup    = (const float*)d_in[1];
    const float* g1     = (const float*)d_in[2];
    const float* be1    = (const float*)d_in[3];
    const float* g2     = (const float*)d_in[4];
    const float* be2    = (const float*)d_in[5];
    const float* Wkv    = (const float*)d_in[6];
    const float* bkv    = (const float*)d_in[7];
    const float* Wproj  = (const float*)d_in[8];
    const float* bproj  = (const float*)d_in[9];
    const float* btab   = (const float*)d_in[10];
    const int*  relidx  = (const int*)d_in[11];
    const float* W1     = (const float*)d_in[12];
    const float* b1     = (const float*)d_in[13];
    const float* W2     = (const float*)d_in[14];
    const float* b2     = (const float*)d_in[15];
    float* xio = (float*)d_out;          // x lives in d_out; k_mlp updates it in place
    bf16* ws = (bf16*)d_ws;              // weight images (~811 KB)

    k_prep<<<198, 256, 0, stream>>>(Wkv, Wproj, W1, W2, ws);
    k_attn<<<4096, 256, 0, stream>>>(skip, xup, g1, be1, ws, bkv,
                                     ws + 73728, bproj, btab, relidx, xio);
    k_mlp<<<2048, 256, 0, stream>>>(xio, g2, be2, ws + 110592, b1, b2);
}